// Round 4
// baseline (161.139 us; speedup 1.0000x reference)
//
#include <hip/hip_runtime.h>
#include <stdint.h>

typedef float  f32x4 __attribute__((ext_vector_type(4)));
typedef __bf16 bf16x8 __attribute__((ext_vector_type(8)));
typedef short  s16x8 __attribute__((ext_vector_type(8)));
typedef unsigned short u16;

static __device__ __forceinline__ u16 f2bf(float f) {
  unsigned u = __float_as_uint(f);
  u += 0x7fffu + ((u >> 16) & 1u);
  return (u16)(u >> 16);
}
static __device__ __forceinline__ float bf2f(u16 u) {
  return __uint_as_float(((unsigned)u) << 16);
}

static __device__ __forceinline__ void async_copy16(void* lds, const void* g) {
  __builtin_amdgcn_global_load_lds(
      (const __attribute__((address_space(1))) unsigned int*)g,
      (__attribute__((address_space(3))) unsigned int*)lds, 16, 0, 0);
}

// ---------------- fp32 -> bf16 convert (weights) ----------------
__global__ __launch_bounds__(256) void cvt_k(const float* __restrict__ in,
                                             u16* __restrict__ out, int n4) {
  int i = blockIdx.x * 256 + threadIdx.x;
  if (i >= n4) return;
  float4 v = reinterpret_cast<const float4*>(in)[i];
  ushort4 o;
  o.x = f2bf(v.x); o.y = f2bf(v.y); o.z = f2bf(v.z); o.w = f2bf(v.w);
  reinterpret_cast<ushort4*>(out)[i] = o;
}

// ---------------- LayerNorm: one block per row, D=1024 ----------------
__global__ __launch_bounds__(256) void ln_k(const float* __restrict__ x,
                                            const float* __restrict__ g,
                                            const float* __restrict__ b,
                                            u16* __restrict__ xn) {
  const int D = 1024;
  const int row = blockIdx.x;
  const int tid = threadIdx.x;
  const float4 v = reinterpret_cast<const float4*>(x + (size_t)row * D)[tid];
  float s  = v.x + v.y + v.z + v.w;
  float s2 = v.x * v.x + v.y * v.y + v.z * v.z + v.w * v.w;
  #pragma unroll
  for (int off = 32; off > 0; off >>= 1) {
    s  += __shfl_down(s, off);
    s2 += __shfl_down(s2, off);
  }
  __shared__ float red[8];
  const int lane = tid & 63, wv = tid >> 6;
  if (lane == 0) { red[wv] = s; red[4 + wv] = s2; }
  __syncthreads();
  s  = red[0] + red[1] + red[2] + red[3];
  s2 = red[4] + red[5] + red[6] + red[7];
  const float mu   = s * (1.0f / D);
  const float var  = s2 * (1.0f / D) - mu * mu;
  const float rstd = rsqrtf(var + 1e-5f);
  const float4 gv = reinterpret_cast<const float4*>(g)[tid];
  const float4 bv = reinterpret_cast<const float4*>(b)[tid];
  ushort4 o;
  o.x = f2bf((v.x - mu) * rstd * gv.x + bv.x);
  o.y = f2bf((v.y - mu) * rstd * gv.y + bv.y);
  o.z = f2bf((v.z - mu) * rstd * gv.z + bv.z);
  o.w = f2bf((v.w - mu) * rstd * gv.w + bv.w);
  reinterpret_cast<ushort4*>(xn + (size_t)row * D)[tid] = o;
}

// ---------------- bf16 GEMM, C = A @ B^T + bias: 256^2, counted-vmcnt ----------------
// BM=BN=256, BK=64, 512 threads (8 waves, 2Mx4N), double-buffered 128KiB LDS.
// LDS row layouts PERMUTED so staging rounds align with phase consumption:
//   A rounds (issue order): tile blocks {0,2,1,3}*64 -> A-h0 = phases P0/P1, A-h1 = P2/P3
//   B rounds: rows regrouped so B-h0 (rows with (r&63)<32) = rounds 0,1; B-h1 = rounds 2,3
// All 8 rounds for tile t+1 issue in P0 of tile t; counted waits vmcnt(10/8/4),
// never 0 in the main loop (T3+T4). setprio around MFMA (T5). XOR swizzle (T2),
// XCD-bijective block swizzle (T1). Epilogue: LDS-staged coalesced C stores; for
// MODE==1 also computes per-chunk EMA partial sums (fused ema_chunk).
static __device__ __forceinline__ s16x8 ldfrag(const u16* b, int row, int ks,
                                               int fkc, int sx) {
  return *reinterpret_cast<const s16x8*>(
      &b[row * 64 + ((((ks << 2) + fkc) ^ sx) << 3)]);
}

template<int MODE>  // 0: fp32 out; 1: bf16 out + EMA chunk partials
__global__ __launch_bounds__(512, 2) void gemm8_k(const u16* __restrict__ A,
                                                  const u16* __restrict__ Bm,
                                                  const float* __restrict__ bias,
                                                  void* __restrict__ Cv,
                                                  const float* __restrict__ alpha,
                                                  float* __restrict__ Lp,
                                                  int M, int N, int K) {
  const int tid  = threadIdx.x;
  const int lane = tid & 63;
  const int wv   = tid >> 6;      // 0..7
  const int wrr  = wv >> 2;       // 0..1  (wave row)
  const int wcc  = wv & 3;        // 0..3  (wave col)
  const int ntN  = N >> 8;
  const int nwg  = (M >> 8) * ntN;
  const int bid  = blockIdx.x;
  const int wgid = (bid & 7) * (nwg >> 3) + (bid >> 3);   // nwg % 8 == 0
  const int mt = wgid / ntN, nt = wgid % ntN;
  const int m0 = mt << 8, n0 = nt << 8;

  __shared__ __align__(16) u16 smem[4 * 16384];   // [A0|A1|B0|B1], 128 KiB

  // ---- staging setup: round r covers LDS rows [64r, 64r+64) of its operand.
  const int u   = tid >> 3;        // row within round
  const int tch = tid & 7;
  const int csw = (tch ^ (u & 7)) << 3;            // inverse-swizzled src col
  const int ldst = u * 64 + (tch << 3);            // linear LDS dest (elem)
  constexpr int amap[4] = {0, 2, 1, 3};
  const u16* gAr[4];
  const u16* gBr[4];
  #pragma unroll
  for (int r = 0; r < 4; ++r) {
    gAr[r] = A + (size_t)(m0 + amap[r] * 64 + u) * K + csw;
    const int l = r * 64 + u;
    const int grow = ((l >> 5) & 3) * 64 + (l >> 7) * 32 + (l & 31);
    gBr[r] = Bm + (size_t)(n0 + grow) * K + csw;
  }

  f32x4 acc[8][4];
  #pragma unroll
  for (int i = 0; i < 8; ++i)
    #pragma unroll
    for (int j = 0; j < 4; ++j) acc[i][j] = f32x4{0.f, 0.f, 0.f, 0.f};

  const int fr  = lane & 15;
  const int fkc = lane >> 4;
  const int sx  = fr & 7;

  const int NK = K >> 6;

#define ISSUE8(nA, nB, koff)                                      \
  async_copy16(&(nA)[ldst],            gAr[0] + (koff));          \
  async_copy16(&(nA)[ldst + 4096],     gAr[1] + (koff));          \
  async_copy16(&(nB)[ldst],            gBr[0] + (koff));          \
  async_copy16(&(nB)[ldst + 4096],     gBr[1] + (koff));          \
  async_copy16(&(nB)[ldst + 2 * 4096], gBr[2] + (koff));          \
  async_copy16(&(nB)[ldst + 3 * 4096], gBr[3] + (koff));          \
  async_copy16(&(nA)[ldst + 2 * 4096], gAr[2] + (koff));          \
  async_copy16(&(nA)[ldst + 3 * 4096], gAr[3] + (koff));

  // prologue: stage tile 0 (rounds in consumption order), wait only first half
  { u16* nA = smem; u16* nB = smem + 32768; ISSUE8(nA, nB, 0) }
  asm volatile("s_waitcnt vmcnt(4)" ::: "memory");
  __builtin_amdgcn_s_barrier();

  s16x8 af[4][2], bfr[2][2];

  for (int kt = 0; kt < NK; ++kt) {
    const int cur = kt & 1;
    const u16* bA = smem + cur * 16384;
    const u16* bB = smem + 32768 + cur * 16384;
    u16* nA = (u16*)(smem + (cur ^ 1) * 16384);
    u16* nB = (u16*)(smem + 32768 + (cur ^ 1) * 16384);
    const bool pf = (kt + 1 < NK);
    const size_t ko = (size_t)(kt + 1) << 6;

    // ---- P0: quadrant (mh0, nh0). reads A-h0 (8) + B-h0 (4). issue all 8 rounds.
    #pragma unroll
    for (int i = 0; i < 4; ++i)
      #pragma unroll
      for (int ks = 0; ks < 2; ++ks)
        af[i][ks] = ldfrag(bA, wrr * 64 + i * 16 + fr, ks, fkc, sx);        // mh=0
    #pragma unroll
    for (int j = 0; j < 2; ++j)
      #pragma unroll
      for (int ks = 0; ks < 2; ++ks)
        bfr[j][ks] = ldfrag(bB, wcc * 32 + j * 16 + fr, ks, fkc, sx);       // nh=0
    if (pf) { ISSUE8(nA, nB, ko) }
    __builtin_amdgcn_s_barrier();
    __builtin_amdgcn_s_setprio(1);
    #pragma unroll
    for (int i = 0; i < 4; ++i)
      #pragma unroll
      for (int j = 0; j < 2; ++j)
        #pragma unroll
        for (int ks = 0; ks < 2; ++ks)
          acc[i][j] = __builtin_amdgcn_mfma_f32_16x16x32_bf16(
              __builtin_bit_cast(bf16x8, af[i][ks]),
              __builtin_bit_cast(bf16x8, bfr[j][ks]), acc[i][j], 0, 0, 0);
    __builtin_amdgcn_s_setprio(0);
    if (pf) asm volatile("s_waitcnt vmcnt(10)" ::: "memory");
    else    asm volatile("s_waitcnt vmcnt(2)" ::: "memory");
    __builtin_amdgcn_s_barrier();

    // ---- P1: quadrant (mh0, nh1). reads B-h1 (4), reuse A.
    #pragma unroll
    for (int j = 0; j < 2; ++j)
      #pragma unroll
      for (int ks = 0; ks < 2; ++ks)
        bfr[j][ks] = ldfrag(bB, 128 + wcc * 32 + j * 16 + fr, ks, fkc, sx); // nh=1
    __builtin_amdgcn_s_barrier();
    __builtin_amdgcn_s_setprio(1);
    #pragma unroll
    for (int i = 0; i < 4; ++i)
      #pragma unroll
      for (int j = 0; j < 2; ++j)
        #pragma unroll
        for (int ks = 0; ks < 2; ++ks)
          acc[i][2 + j] = __builtin_amdgcn_mfma_f32_16x16x32_bf16(
              __builtin_bit_cast(bf16x8, af[i][ks]),
              __builtin_bit_cast(bf16x8, bfr[j][ks]), acc[i][2 + j], 0, 0, 0);
    __builtin_amdgcn_s_setprio(0);
    if (pf) asm volatile("s_waitcnt vmcnt(8)" ::: "memory");
    else    asm volatile("s_waitcnt vmcnt(0)" ::: "memory");
    __builtin_amdgcn_s_barrier();

    // ---- P2: quadrant (mh1, nh1). reads A-h1 (8), reuse B.
    #pragma unroll
    for (int i = 0; i < 4; ++i)
      #pragma unroll
      for (int ks = 0; ks < 2; ++ks)
        af[i][ks] = ldfrag(bA, 128 + wrr * 64 + i * 16 + fr, ks, fkc, sx);  // mh=1
    __builtin_amdgcn_s_barrier();
    __builtin_amdgcn_s_setprio(1);
    #pragma unroll
    for (int i = 0; i < 4; ++i)
      #pragma unroll
      for (int j = 0; j < 2; ++j)
        #pragma unroll
        for (int ks = 0; ks < 2; ++ks)
          acc[4 + i][2 + j] = __builtin_amdgcn_mfma_f32_16x16x32_bf16(
              __builtin_bit_cast(bf16x8, af[i][ks]),
              __builtin_bit_cast(bf16x8, bfr[j][ks]), acc[4 + i][2 + j], 0, 0, 0);
    __builtin_amdgcn_s_setprio(0);
    __builtin_amdgcn_s_barrier();

    // ---- P3: quadrant (mh1, nh0). reads B-h0 (4, long resident), reuse A.
    #pragma unroll
    for (int j = 0; j < 2; ++j)
      #pragma unroll
      for (int ks = 0; ks < 2; ++ks)
        bfr[j][ks] = ldfrag(bB, wcc * 32 + j * 16 + fr, ks, fkc, sx);       // nh=0
    __builtin_amdgcn_s_barrier();
    __builtin_amdgcn_s_setprio(1);
    #pragma unroll
    for (int i = 0; i < 4; ++i)
      #pragma unroll
      for (int j = 0; j < 2; ++j)
        #pragma unroll
        for (int ks = 0; ks < 2; ++ks)
          acc[4 + i][j] = __builtin_amdgcn_mfma_f32_16x16x32_bf16(
              __builtin_bit_cast(bf16x8, af[i][ks]),
              __builtin_bit_cast(bf16x8, bfr[j][ks]), acc[4 + i][j], 0, 0, 0);
    __builtin_amdgcn_s_setprio(0);
    asm volatile("s_waitcnt vmcnt(4)" ::: "memory");  // guards next-tile P0 reads
    __builtin_amdgcn_s_barrier();
  }
#undef ISSUE8

  // ---- epilogue: LDS-staged coalesced C write (+ fused EMA chunk partials) ----
  float* sC = (float*)smem;            // 128 rows x 256 cols fp32 = 128 KiB
  const int cr = (lane >> 4) << 2;
  const int cc = lane & 15;
  float bv[4];
  #pragma unroll
  for (int nj = 0; nj < 4; ++nj) bv[nj] = bias[n0 + wcc * 64 + nj * 16 + cc];

  #pragma unroll
  for (int p = 0; p < 2; ++p) {
    __syncthreads();                   // prev pass / K-loop reads done
    if (wrr == p) {
      #pragma unroll
      for (int mi = 0; mi < 8; ++mi)
        #pragma unroll
        for (int nj = 0; nj < 4; ++nj)
          #pragma unroll
          for (int rr = 0; rr < 4; ++rr) {
            const int row = mi * 16 + cr + rr;
            const int col = wcc * 64 + nj * 16 + cc;
            sC[row * 256 + (col ^ ((row & 4) << 2))] = acc[mi][nj][rr] + bv[nj];
          }
    }
    __syncthreads();
    // coalesced store: 16B/lane
    #pragma unroll 4
    for (int it = 0; it < 16; ++it) {
      const int row  = it * 8 + wv;
      const int col0 = (tid & 63) * 4;
      f32x4 v = *(const f32x4*)&sC[row * 256 + (col0 ^ ((row & 4) << 2))];
      const size_t goff = (size_t)(m0 + p * 128 + row) * N + n0 + col0;
      if (MODE == 1) {
        ushort4 o; o.x = f2bf(v[0]); o.y = f2bf(v[1]); o.z = f2bf(v[2]); o.w = f2bf(v[3]);
        *(ushort4*)&((u16*)Cv)[goff] = o;
      } else {
        *(f32x4*)&((float*)Cv)[goff] = v;
      }
    }
    if (MODE == 1 && tid < 256) {
      // per-chunk EMA local sum over rows 1..127 (row-0 boundary term is
      // added exactly by the carry kernel). Chunk == this 128-row pass.
      const int col = tid;
      const int hh = (n0 + col) >> 7;
      const float a = 1.0f / (1.0f + __expf(-alpha[hh]));
      const float rw = 1.0f - a;
      float prev = sC[col];            // row 0 (swizzle bits 0 for row 0)
      float L = 0.f;
      int t = 1;
      for (; t + 8 <= 128; t += 8) {
        float w0 = sC[(t+0)*256 + (col ^ (((t+0)&4)<<2))];
        float w1 = sC[(t+1)*256 + (col ^ (((t+1)&4)<<2))];
        float w2 = sC[(t+2)*256 + (col ^ (((t+2)&4)<<2))];
        float w3 = sC[(t+3)*256 + (col ^ (((t+3)&4)<<2))];
        float w4 = sC[(t+4)*256 + (col ^ (((t+4)&4)<<2))];
        float w5 = sC[(t+5)*256 + (col ^ (((t+5)&4)<<2))];
        float w6 = sC[(t+6)*256 + (col ^ (((t+6)&4)<<2))];
        float w7 = sC[(t+7)*256 + (col ^ (((t+7)&4)<<2))];
        L = rw * L + a * (w0 - prev);
        L = rw * L + a * (w1 - w0);
        L = rw * L + a * (w2 - w1);
        L = rw * L + a * (w3 - w2);
        L = rw * L + a * (w4 - w3);
        L = rw * L + a * (w5 - w4);
        L = rw * L + a * (w6 - w5);
        L = rw * L + a * (w7 - w6);
        prev = w7;
      }
      for (; t < 128; ++t) {
        float w = sC[t*256 + (col ^ ((t&4)<<2))];
        L = rw * L + a * (w - prev); prev = w;
      }
      const int bb = m0 >> 12;
      const int q  = ((m0 >> 7) & 31) + p;
      Lp[((size_t)bb * 32 + q) * 1024 + n0 + col] = L;
    }
  }
}

// ---------------- EMA carry combine (+ exact chunk-boundary terms) ----------------
// Input cr holds L' (rows 1..127 partials from GEMM1). Adds boundary term
// a*r^127*(v0 - v_{-1}), then sequentially combines: carry-out -> incoming O.
__global__ __launch_bounds__(256) void ema_carry_k(const u16* __restrict__ xpb,
                                                   const float* __restrict__ alpha,
                                                   const float* __restrict__ init,
                                                   float* __restrict__ carry) {
  const int Dd = 1024, nCh = 32;
  const int idx = blockIdx.x * 256 + threadIdx.x;  // 0..B*D-1
  const int c  = idx & (Dd - 1);
  const int bb = idx >> 10;
  const int h = c >> 7;
  const float a = 1.0f / (1.0f + __expf(-alpha[h]));
  const float r = 1.0f - a;
  // r^127 via product of r^(2^i), i=0..6 (127 = 1111111b); r^128 = r^127*r
  float q_ = r, r127 = 1.0f;
  #pragma unroll
  for (int s = 0; s < 7; ++s) { r127 *= q_; q_ *= q_; }
  const float rT = r127 * r;
  float cin = init[c];
  float prevv = cin;                               // v_{-1} for chunk 0
  for (int q = 0; q < nCh; ++q) {
    const size_t rowb = (size_t)bb * 4096 + (size_t)q * 128;
    const float v0 = bf2f(xpb[rowb * Dd + c]);
    const size_t off = ((size_t)bb * nCh + q) * Dd + c;
    const float L = carry[off] + a * r127 * (v0 - prevv);
    carry[off] = cin;                              // incoming O for chunk q
    cin = rT * cin + L;
    prevv = bf2f(xpb[(rowb + 127) * Dd + c]);      // v_{-1} for chunk q+1
  }
}

__global__ __launch_bounds__(256) void ema_apply_k(const u16* __restrict__ xp,
                                                   const float* __restrict__ alpha,
                                                   const float* __restrict__ init,
                                                   const float* __restrict__ carry,
                                                   u16* __restrict__ ob) {
  const int Nn = 4096, Dd = 1024, T = 128, nCh = 32;
  int bid = blockIdx.x;
  const int cg = bid & 1;  bid >>= 1;
  const int q  = bid & 31; bid >>= 5;
  const int bb = bid;
  const int c = cg * 512 + threadIdx.x * 2;
  const int h = c >> 7;
  const float a = 1.0f / (1.0f + __expf(-alpha[h]));
  const float r = 1.0f - a;
  const u16* px = xp + ((size_t)bb * Nn + (size_t)q * T) * Dd + c;
  u16* po = ob + ((size_t)bb * Nn + (size_t)q * T) * Dd + c;
  float2 Oin = *(const float2*)(carry + ((size_t)bb * nCh + q) * Dd + c);
  float O0 = Oin.x, O1 = Oin.y;
  float p0, p1;
  if (q == 0) { p0 = init[c]; p1 = init[c + 1]; }
  else { ushort2 pv = *(const ushort2*)(px - Dd); p0 = bf2f(pv.x); p1 = bf2f(pv.y); }
  #pragma unroll 4
  for (int t = 0; t < T; ++t) {
    ushort2 v = *(const ushort2*)(px + (size_t)t * Dd);
    float v0 = bf2f(v.x), v1 = bf2f(v.y);
    O0 = r * O0 + a * (v0 - p0);
    O1 = r * O1 + a * (v1 - p1);
    p0 = v0; p1 = v1;
    ushort2 o; o.x = f2bf(O0); o.y = f2bf(O1);
    *(ushort2*)(po + (size_t)t * Dd) = o;
  }
}

extern "C" void kernel_launch(void* const* d_in, const int* in_sizes, int n_in,
                              void* d_out, int out_size, void* d_ws, size_t ws_size,
                              hipStream_t stream) {
  const float* x     = (const float*)d_in[0];
  const float* ln_g  = (const float*)d_in[1];
  const float* ln_b  = (const float*)d_in[2];
  const float* w_in  = (const float*)d_in[3];
  const float* b_in  = (const float*)d_in[4];
  const float* init  = (const float*)d_in[5];
  const float* alpha = (const float*)d_in[6];
  const float* w_out = (const float*)d_in[7];
  const float* b_out = (const float*)d_in[8];
  float* out = (float*)d_out;

  const int B = 4, N = 4096, D = 1024;
  const int M = B * N;  // 16384

  char* p = (char*)d_ws;
  u16*   xn  = (u16*)p; p += (size_t)M * D * sizeof(u16);      // 32 MB  LN output bf16
  u16*   wi  = (u16*)p; p += (size_t)D * D * sizeof(u16);      // 2 MB   w_in bf16
  u16*   wo  = (u16*)p; p += (size_t)D * D * sizeof(u16);      // 2 MB   w_out bf16
  u16*   xpb = (u16*)p; p += (size_t)M * D * sizeof(u16);      // 32 MB  project_in out bf16
  float* cr  = (float*)p; p += (size_t)B * 32 * D * sizeof(float); // 512 KB L-partials/carries
  u16*   ob  = (u16*)p;                                         // 32 MB  EMA out bf16

  const int n4 = D * D / 4;
  cvt_k<<<dim3((n4 + 255) / 256), dim3(256), 0, stream>>>(w_in, wi, n4);
  cvt_k<<<dim3((n4 + 255) / 256), dim3(256), 0, stream>>>(w_out, wo, n4);
  ln_k<<<dim3(M), dim3(256), 0, stream>>>(x, ln_g, ln_b, xn);
  gemm8_k<1><<<dim3((M / 256) * (D / 256)), dim3(512), 0, stream>>>(
      xn, wi, b_in, xpb, alpha, cr, M, D, D);
  ema_carry_k<<<dim3(B * D / 256), dim3(256), 0, stream>>>(xpb, alpha, init, cr);
  ema_apply_k<<<dim3(B * 32 * 2), dim3(256), 0, stream>>>(xpb, alpha, init, cr, ob);
  gemm8_k<0><<<dim3((M / 256) * (D / 256)), dim3(512), 0, stream>>>(
      ob, wo, b_out, out, nullptr, nullptr, M, D, D);
}

// Round 5
// 160.730 us; speedup vs baseline: 1.0025x; 1.0025x over previous
//
#include <hip/hip_runtime.h>
#include <stdint.h>

typedef float  f32x4 __attribute__((ext_vector_type(4)));
typedef __bf16 bf16x8 __attribute__((ext_vector_type(8)));
typedef short  s16x8 __attribute__((ext_vector_type(8)));
typedef unsigned short u16;

static __device__ __forceinline__ u16 f2bf(float f) {
  unsigned u = __float_as_uint(f);
  u += 0x7fffu + ((u >> 16) & 1u);
  return (u16)(u >> 16);
}
static __device__ __forceinline__ float bf2f(u16 u) {
  return __uint_as_float(((unsigned)u) << 16);
}

static __device__ __forceinline__ void async_copy16(void* lds, const void* g) {
  __builtin_amdgcn_global_load_lds(
      (const __attribute__((address_space(1))) unsigned int*)g,
      (__attribute__((address_space(3))) unsigned int*)lds, 16, 0, 0);
}

// ---------------- fp32 -> bf16 convert (weights) ----------------
__global__ __launch_bounds__(256) void cvt_k(const float* __restrict__ in,
                                             u16* __restrict__ out, int n4) {
  int i = blockIdx.x * 256 + threadIdx.x;
  if (i >= n4) return;
  float4 v = reinterpret_cast<const float4*>(in)[i];
  ushort4 o;
  o.x = f2bf(v.x); o.y = f2bf(v.y); o.z = f2bf(v.z); o.w = f2bf(v.w);
  reinterpret_cast<ushort4*>(out)[i] = o;
}

// ---------------- LayerNorm: one block per row, D=1024 ----------------
__global__ __launch_bounds__(256) void ln_k(const float* __restrict__ x,
                                            const float* __restrict__ g,
                                            const float* __restrict__ b,
                                            u16* __restrict__ xn) {
  const int D = 1024;
  const int row = blockIdx.x;
  const int tid = threadIdx.x;
  const float4 v = reinterpret_cast<const float4*>(x + (size_t)row * D)[tid];
  float s  = v.x + v.y + v.z + v.w;
  float s2 = v.x * v.x + v.y * v.y + v.z * v.z + v.w * v.w;
  #pragma unroll
  for (int off = 32; off > 0; off >>= 1) {
    s  += __shfl_down(s, off);
    s2 += __shfl_down(s2, off);
  }
  __shared__ float red[8];
  const int lane = tid & 63, wv = tid >> 6;
  if (lane == 0) { red[wv] = s; red[4 + wv] = s2; }
  __syncthreads();
  s  = red[0] + red[1] + red[2] + red[3];
  s2 = red[4] + red[5] + red[6] + red[7];
  const float mu   = s * (1.0f / D);
  const float var  = s2 * (1.0f / D) - mu * mu;
  const float rstd = rsqrtf(var + 1e-5f);
  const float4 gv = reinterpret_cast<const float4*>(g)[tid];
  const float4 bv = reinterpret_cast<const float4*>(b)[tid];
  ushort4 o;
  o.x = f2bf((v.x - mu) * rstd * gv.x + bv.x);
  o.y = f2bf((v.y - mu) * rstd * gv.y + bv.y);
  o.z = f2bf((v.z - mu) * rstd * gv.z + bv.z);
  o.w = f2bf((v.w - mu) * rstd * gv.w + bv.w);
  reinterpret_cast<ushort4*>(xn + (size_t)row * D)[tid] = o;
}

// ---------------- bf16 GEMM, C = A @ B^T + bias: 256^2, ring-4 half-tiles ----
// BM=BN=256, BK=64, 512 threads (8 waves, 2Mx4N), 128KiB LDS as 4 half-tile
// ring per operand. Issue order matches consumption order; counted vmcnt(8/6)
// waits give every staged half >=3 phases of slack (T3+T4). setprio (T5),
// XOR swizzle (T2), XCD-bijective block swizzle (T1). Epilogue: LDS-staged
// coalesced stores; MODE==1 fuses EMA chunk partials.
static __device__ __forceinline__ s16x8 ldfrag(const u16* b, int row, int ks,
                                               int fkc, int sx) {
  return *reinterpret_cast<const s16x8*>(
      &b[row * 64 + ((((ks << 2) + fkc) ^ sx) << 3)]);
}

template<int MODE>  // 0: fp32 out; 1: bf16 out + EMA chunk partials
__global__ __launch_bounds__(512, 2) void gemm8_k(const u16* __restrict__ A,
                                                  const u16* __restrict__ Bm,
                                                  const float* __restrict__ bias,
                                                  void* __restrict__ Cv,
                                                  const float* __restrict__ alpha,
                                                  float* __restrict__ Lp,
                                                  int M, int N, int K) {
  const int tid  = threadIdx.x;
  const int lane = tid & 63;
  const int wv   = tid >> 6;      // 0..7
  const int wrr  = wv >> 2;       // 0..1  (wave row)
  const int wcc  = wv & 3;        // 0..3  (wave col)
  const int ntN  = N >> 8;
  const int nwg  = (M >> 8) * ntN;
  const int bid  = blockIdx.x;
  const int wgid = (bid & 7) * (nwg >> 3) + (bid >> 3);   // nwg % 8 == 0
  const int mt = wgid / ntN, nt = wgid % ntN;
  const int m0 = mt << 8, n0 = nt << 8;

  __shared__ __align__(16) u16 smem[4 * 16384];   // A:[0,32K) B:[32K,64K) u16

  // staging: LDS row l holds global A row (amap) / B row (grow) so that the
  // layout is wave-major (verified R4). Half = 2 rounds = 128 LDS rows.
  const int u   = tid >> 3;
  const int tch = tid & 7;
  const int csw = (tch ^ (u & 7)) << 3;            // inverse-swizzled src col
  const int ldst = u * 64 + (tch << 3);            // linear LDS dest (elem)
  constexpr int amap[4] = {0, 2, 1, 3};
  const u16* gAr[4];
  const u16* gBr[4];
  #pragma unroll
  for (int r = 0; r < 4; ++r) {
    gAr[r] = A + (size_t)(m0 + amap[r] * 64 + u) * K + csw;
    const int l = r * 64 + u;
    const int grow = ((l >> 5) & 3) * 64 + (l >> 7) * 32 + (l & 31);
    gBr[r] = Bm + (size_t)(n0 + grow) * K + csw;
  }

  f32x4 acc[8][4];
  #pragma unroll
  for (int i = 0; i < 8; ++i)
    #pragma unroll
    for (int j = 0; j < 4; ++j) acc[i][j] = f32x4{0.f, 0.f, 0.f, 0.f};

  const int fr  = lane & 15;
  const int fkc = lane >> 4;
  const int sx  = fr & 7;
  const int NK  = K >> 6;   // >= 3 assumed (here 16)

#define ST2(dst, pa, pb, ko) \
  async_copy16(&(dst)[ldst], (pa) + (ko)); \
  async_copy16(&(dst)[ldst + 4096], (pb) + (ko));

  // prologue issue order: Bh0(0) Ah1(0) Ah0(0) Bh1(0) Bh0(1) Ah1(1)
  {
    u16* A0 = smem;         u16* A1 = smem + 16384;
    u16* B0 = smem + 32768; u16* B1 = smem + 49152;
    ST2(B0,        gBr[0], gBr[1], 0)
    ST2(A0 + 8192, gAr[2], gAr[3], 0)
    ST2(A0,        gAr[0], gAr[1], 0)
    ST2(B0 + 8192, gBr[2], gBr[3], 0)
    ST2(B1,        gBr[0], gBr[1], 64)
    ST2(A1 + 8192, gAr[2], gAr[3], 64)
  }
  asm volatile("s_waitcnt vmcnt(6)" ::: "memory");
  __builtin_amdgcn_s_barrier();

  s16x8 af[4][2], bfr[2][2];

  for (int kt = 0; kt < NK; ++kt) {
    const int cur = kt & 1;
    u16* bA = smem + cur * 16384;
    u16* bB = smem + 32768 + cur * 16384;
    u16* nA = smem + (cur ^ 1) * 16384;
    u16* nB = smem + 32768 + (cur ^ 1) * 16384;
    const size_t ko1 = (size_t)(kt + 1) << 6;
    const size_t ko2 = (size_t)(kt + 2) << 6;

    // ---- P0: quad (mh0,nh0); read Ah0+Bh0; stage Ah0(kt+1) -> nA
    #pragma unroll
    for (int i = 0; i < 4; ++i)
      #pragma unroll
      for (int ks = 0; ks < 2; ++ks)
        af[i][ks] = ldfrag(bA, wrr * 64 + i * 16 + fr, ks, fkc, sx);
    #pragma unroll
    for (int j = 0; j < 2; ++j)
      #pragma unroll
      for (int ks = 0; ks < 2; ++ks)
        bfr[j][ks] = ldfrag(bB, wcc * 32 + j * 16 + fr, ks, fkc, sx);
    if (kt + 1 < NK) { ST2(nA, gAr[0], gAr[1], ko1) }
    __builtin_amdgcn_s_barrier();
    __builtin_amdgcn_s_setprio(1);
    #pragma unroll
    for (int i = 0; i < 4; ++i)
      #pragma unroll
      for (int j = 0; j < 2; ++j)
        #pragma unroll
        for (int ks = 0; ks < 2; ++ks)
          acc[i][j] = __builtin_amdgcn_mfma_f32_16x16x32_bf16(
              __builtin_bit_cast(bf16x8, af[i][ks]),
              __builtin_bit_cast(bf16x8, bfr[j][ks]), acc[i][j], 0, 0, 0);
    __builtin_amdgcn_s_setprio(0);
    __builtin_amdgcn_s_barrier();

    // ---- P1: quad (mh1,nh0); read Ah1; stage Bh1(kt+1) -> nB
    #pragma unroll
    for (int i = 0; i < 4; ++i)
      #pragma unroll
      for (int ks = 0; ks < 2; ++ks)
        af[i][ks] = ldfrag(bA, 128 + wrr * 64 + i * 16 + fr, ks, fkc, sx);
    if (kt + 1 < NK) { ST2(nB + 8192, gBr[2], gBr[3], ko1) }
    __builtin_amdgcn_s_barrier();
    __builtin_amdgcn_s_setprio(1);
    #pragma unroll
    for (int i = 0; i < 4; ++i)
      #pragma unroll
      for (int j = 0; j < 2; ++j)
        #pragma unroll
        for (int ks = 0; ks < 2; ++ks)
          acc[4 + i][j] = __builtin_amdgcn_mfma_f32_16x16x32_bf16(
              __builtin_bit_cast(bf16x8, af[i][ks]),
              __builtin_bit_cast(bf16x8, bfr[j][ks]), acc[4 + i][j], 0, 0, 0);
    __builtin_amdgcn_s_setprio(0);
    if (kt == NK - 1) { asm volatile("s_waitcnt vmcnt(0)" ::: "memory"); }
    else              { asm volatile("s_waitcnt vmcnt(8)" ::: "memory"); }
    __builtin_amdgcn_s_barrier();

    // ---- P2: quad (mh1,nh1); read Bh1; stage Bh0(kt+2) -> bB (current buf)
    #pragma unroll
    for (int j = 0; j < 2; ++j)
      #pragma unroll
      for (int ks = 0; ks < 2; ++ks)
        bfr[j][ks] = ldfrag(bB, 128 + wcc * 32 + j * 16 + fr, ks, fkc, sx);
    if (kt + 2 < NK) { ST2(bB, gBr[0], gBr[1], ko2) }
    __builtin_amdgcn_s_barrier();
    __builtin_amdgcn_s_setprio(1);
    #pragma unroll
    for (int i = 0; i < 4; ++i)
      #pragma unroll
      for (int j = 0; j < 2; ++j)
        #pragma unroll
        for (int ks = 0; ks < 2; ++ks)
          acc[4 + i][2 + j] = __builtin_amdgcn_mfma_f32_16x16x32_bf16(
              __builtin_bit_cast(bf16x8, af[i][ks]),
              __builtin_bit_cast(bf16x8, bfr[j][ks]), acc[4 + i][2 + j], 0, 0, 0);
    __builtin_amdgcn_s_setprio(0);
    __builtin_amdgcn_s_barrier();

    // ---- P3: quad (mh0,nh1); re-read Ah0; stage Ah1(kt+2) -> bA (current buf)
    #pragma unroll
    for (int i = 0; i < 4; ++i)
      #pragma unroll
      for (int ks = 0; ks < 2; ++ks)
        af[i][ks] = ldfrag(bA, wrr * 64 + i * 16 + fr, ks, fkc, sx);
    if (kt + 2 < NK) { ST2(bA + 8192, gAr[2], gAr[3], ko2) }
    __builtin_amdgcn_s_barrier();
    __builtin_amdgcn_s_setprio(1);
    #pragma unroll
    for (int i = 0; i < 4; ++i)
      #pragma unroll
      for (int j = 0; j < 2; ++j)
        #pragma unroll
        for (int ks = 0; ks < 2; ++ks)
          acc[i][2 + j] = __builtin_amdgcn_mfma_f32_16x16x32_bf16(
              __builtin_bit_cast(bf16x8, af[i][ks]),
              __builtin_bit_cast(bf16x8, bfr[j][ks]), acc[i][2 + j], 0, 0, 0);
    __builtin_amdgcn_s_setprio(0);
    if (kt < NK - 2)       { asm volatile("s_waitcnt vmcnt(6)" ::: "memory"); }
    else if (kt == NK - 2) { asm volatile("s_waitcnt vmcnt(2)" ::: "memory"); }
    __builtin_amdgcn_s_barrier();
  }
#undef ST2

  // ---- epilogue: LDS-staged coalesced C write (+ fused EMA chunk partials) ----
  float* sC = (float*)smem;            // 128 rows x 256 cols fp32 = 128 KiB
  const int cr = (lane >> 4) << 2;
  const int cc = lane & 15;
  float bv[4];
  #pragma unroll
  for (int nj = 0; nj < 4; ++nj) bv[nj] = bias[n0 + wcc * 64 + nj * 16 + cc];

  #pragma unroll
  for (int p = 0; p < 2; ++p) {
    __syncthreads();                   // prev pass / K-loop reads done
    if (wrr == p) {
      #pragma unroll
      for (int mi = 0; mi < 8; ++mi)
        #pragma unroll
        for (int nj = 0; nj < 4; ++nj)
          #pragma unroll
          for (int rr = 0; rr < 4; ++rr) {
            const int row = mi * 16 + cr + rr;
            const int col = wcc * 64 + nj * 16 + cc;
            sC[row * 256 + (col ^ ((row & 4) << 2))] = acc[mi][nj][rr] + bv[nj];
          }
    }
    __syncthreads();
    // coalesced store: 16B/lane
    #pragma unroll 4
    for (int it = 0; it < 16; ++it) {
      const int row  = it * 8 + wv;
      const int col0 = (tid & 63) * 4;
      f32x4 v = *(const f32x4*)&sC[row * 256 + (col0 ^ ((row & 4) << 2))];
      const size_t goff = (size_t)(m0 + p * 128 + row) * N + n0 + col0;
      if (MODE == 1) {
        ushort4 o; o.x = f2bf(v[0]); o.y = f2bf(v[1]); o.z = f2bf(v[2]); o.w = f2bf(v[3]);
        *(ushort4*)&((u16*)Cv)[goff] = o;
      } else {
        *(f32x4*)&((float*)Cv)[goff] = v;
      }
    }
    if (MODE == 1 && tid < 256) {
      // per-chunk EMA local sum over rows 1..127 (row-0 boundary term added
      // exactly by the carry kernel). Chunk == this 128-row pass.
      const int col = tid;
      const int hh = (n0 + col) >> 7;
      const float a = 1.0f / (1.0f + __expf(-alpha[hh]));
      const float rw = 1.0f - a;
      float prev = sC[col];            // row 0 (swizzle bits 0 for row 0)
      float L = 0.f;
      int t = 1;
      for (; t + 8 <= 128; t += 8) {
        float w0 = sC[(t+0)*256 + (col ^ (((t+0)&4)<<2))];
        float w1 = sC[(t+1)*256 + (col ^ (((t+1)&4)<<2))];
        float w2 = sC[(t+2)*256 + (col ^ (((t+2)&4)<<2))];
        float w3 = sC[(t+3)*256 + (col ^ (((t+3)&4)<<2))];
        float w4 = sC[(t+4)*256 + (col ^ (((t+4)&4)<<2))];
        float w5 = sC[(t+5)*256 + (col ^ (((t+5)&4)<<2))];
        float w6 = sC[(t+6)*256 + (col ^ (((t+6)&4)<<2))];
        float w7 = sC[(t+7)*256 + (col ^ (((t+7)&4)<<2))];
        L = rw * L + a * (w0 - prev);
        L = rw * L + a * (w1 - w0);
        L = rw * L + a * (w2 - w1);
        L = rw * L + a * (w3 - w2);
        L = rw * L + a * (w4 - w3);
        L = rw * L + a * (w5 - w4);
        L = rw * L + a * (w6 - w5);
        L = rw * L + a * (w7 - w6);
        prev = w7;
      }
      for (; t < 128; ++t) {
        float w = sC[t*256 + (col ^ ((t&4)<<2))];
        L = rw * L + a * (w - prev); prev = w;
      }
      const int bb = m0 >> 12;
      const int q  = ((m0 >> 7) & 31) + p;
      Lp[((size_t)bb * 32 + q) * 1024 + n0 + col] = L;
    }
  }
}

// ---------------- EMA carry combine (+ exact chunk-boundary terms) ----------------
__global__ __launch_bounds__(256) void ema_carry_k(const u16* __restrict__ xpb,
                                                   const float* __restrict__ alpha,
                                                   const float* __restrict__ init,
                                                   float* __restrict__ carry) {
  const int Dd = 1024, nCh = 32;
  const int idx = blockIdx.x * 256 + threadIdx.x;  // 0..B*D-1
  const int c  = idx & (Dd - 1);
  const int bb = idx >> 10;
  const int h = c >> 7;
  const float a = 1.0f / (1.0f + __expf(-alpha[h]));
  const float r = 1.0f - a;
  float q_ = r, r127 = 1.0f;
  #pragma unroll
  for (int s = 0; s < 7; ++s) { r127 *= q_; q_ *= q_; }
  const float rT = r127 * r;
  float cin = init[c];
  float prevv = cin;                               // v_{-1} for chunk 0
  for (int q = 0; q < nCh; ++q) {
    const size_t rowb = (size_t)bb * 4096 + (size_t)q * 128;
    const float v0 = bf2f(xpb[rowb * Dd + c]);
    const size_t off = ((size_t)bb * nCh + q) * Dd + c;
    const float L = carry[off] + a * r127 * (v0 - prevv);
    carry[off] = cin;                              // incoming O for chunk q
    cin = rT * cin + L;
    prevv = bf2f(xpb[(rowb + 127) * Dd + c]);      // v_{-1} for chunk q+1
  }
}

__global__ __launch_bounds__(256) void ema_apply_k(const u16* __restrict__ xp,
                                                   const float* __restrict__ alpha,
                                                   const float* __restrict__ init,
                                                   const float* __restrict__ carry,
                                                   u16* __restrict__ ob) {
  const int Nn = 4096, Dd = 1024, T = 128, nCh = 32;
  int bid = blockIdx.x;
  const int cg = bid & 1;  bid >>= 1;
  const int q  = bid & 31; bid >>= 5;
  const int bb = bid;
  const int c = cg * 512 + threadIdx.x * 2;
  const int h = c >> 7;
  const float a = 1.0f / (1.0f + __expf(-alpha[h]));
  const float r = 1.0f - a;
  const u16* px = xp + ((size_t)bb * Nn + (size_t)q * T) * Dd + c;
  u16* po = ob + ((size_t)bb * Nn + (size_t)q * T) * Dd + c;
  float2 Oin = *(const float2*)(carry + ((size_t)bb * nCh + q) * Dd + c);
  float O0 = Oin.x, O1 = Oin.y;
  float p0, p1;
  if (q == 0) { p0 = init[c]; p1 = init[c + 1]; }
  else { ushort2 pv = *(const ushort2*)(px - Dd); p0 = bf2f(pv.x); p1 = bf2f(pv.y); }
  #pragma unroll 4
  for (int t = 0; t < T; ++t) {
    ushort2 v = *(const ushort2*)(px + (size_t)t * Dd);
    float v0 = bf2f(v.x), v1 = bf2f(v.y);
    O0 = r * O0 + a * (v0 - p0);
    O1 = r * O1 + a * (v1 - p1);
    p0 = v0; p1 = v1;
    ushort2 o; o.x = f2bf(O0); o.y = f2bf(O1);
    *(ushort2*)(po + (size_t)t * Dd) = o;
  }
}

extern "C" void kernel_launch(void* const* d_in, const int* in_sizes, int n_in,
                              void* d_out, int out_size, void* d_ws, size_t ws_size,
                              hipStream_t stream) {
  const float* x     = (const float*)d_in[0];
  const float* ln_g  = (const float*)d_in[1];
  const float* ln_b  = (const float*)d_in[2];
  const float* w_in  = (const float*)d_in[3];
  const float* b_in  = (const float*)d_in[4];
  const float* init  = (const float*)d_in[5];
  const float* alpha = (const float*)d_in[6];
  const float* w_out = (const float*)d_in[7];
  const float* b_out = (const float*)d_in[8];
  float* out = (float*)d_out;

  const int B = 4, N = 4096, D = 1024;
  const int M = B * N;  // 16384

  char* p = (char*)d_ws;
  u16*   xn  = (u16*)p; p += (size_t)M * D * sizeof(u16);      // 32 MB  LN output bf16
  u16*   wi  = (u16*)p; p += (size_t)D * D * sizeof(u16);      // 2 MB   w_in bf16
  u16*   wo  = (u16*)p; p += (size_t)D * D * sizeof(u16);      // 2 MB   w_out bf16
  u16*   xpb = (u16*)p; p += (size_t)M * D * sizeof(u16);      // 32 MB  project_in out bf16
  float* cr  = (float*)p; p += (size_t)B * 32 * D * sizeof(float); // 512 KB L-partials/carries
  u16*   ob  = (u16*)p;                                         // 32 MB  EMA out bf16

  const int n4 = D * D / 4;
  cvt_k<<<dim3((n4 + 255) / 256), dim3(256), 0, stream>>>(w_in, wi, n4);
  cvt_k<<<dim3((n4 + 255) / 256), dim3(256), 0, stream>>>(w_out, wo, n4);
  ln_k<<<dim3(M), dim3(256), 0, stream>>>(x, ln_g, ln_b, xn);
  gemm8_k<1><<<dim3((M / 256) * (D / 256)), dim3(512), 0, stream>>>(
      xn, wi, b_in, xpb, alpha, cr, M, D, D);
  ema_carry_k<<<dim3(B * D / 256), dim3(256), 0, stream>>>(xpb, alpha, init, cr);
  ema_apply_k<<<dim3(B * 32 * 2), dim3(256), 0, stream>>>(xpb, alpha, init, cr, ob);
  gemm8_k<0><<<dim3((M / 256) * (D / 256)), dim3(512), 0, stream>>>(
      ob, wo, b_out, out, nullptr, nullptr, M, D, D);
}

// Round 6
// 160.703 us; speedup vs baseline: 1.0027x; 1.0002x over previous
//
#include <hip/hip_runtime.h>
#include <stdint.h>

typedef float  f32x4 __attribute__((ext_vector_type(4)));
typedef __bf16 bf16x8 __attribute__((ext_vector_type(8)));
typedef short  s16x8 __attribute__((ext_vector_type(8)));
typedef unsigned short u16;

static __device__ __forceinline__ u16 f2bf(float f) {
  unsigned u = __float_as_uint(f);
  u += 0x7fffu + ((u >> 16) & 1u);
  return (u16)(u >> 16);
}
static __device__ __forceinline__ float bf2f(u16 u) {
  return __uint_as_float(((unsigned)u) << 16);
}

static __device__ __forceinline__ void async_copy16(void* lds, const void* g) {
  __builtin_amdgcn_global_load_lds(
      (const __attribute__((address_space(1))) unsigned int*)g,
      (__attribute__((address_space(3))) unsigned int*)lds, 16, 0, 0);
}

// ---------------- fp32 -> bf16 convert (weights) ----------------
__global__ __launch_bounds__(256) void cvt_k(const float* __restrict__ in,
                                             u16* __restrict__ out, int n4) {
  int i = blockIdx.x * 256 + threadIdx.x;
  if (i >= n4) return;
  float4 v = reinterpret_cast<const float4*>(in)[i];
  ushort4 o;
  o.x = f2bf(v.x); o.y = f2bf(v.y); o.z = f2bf(v.z); o.w = f2bf(v.w);
  reinterpret_cast<ushort4*>(out)[i] = o;
}

// ---------------- LayerNorm: one block per row, D=1024 ----------------
__global__ __launch_bounds__(256) void ln_k(const float* __restrict__ x,
                                            const float* __restrict__ g,
                                            const float* __restrict__ b,
                                            u16* __restrict__ xn) {
  const int D = 1024;
  const int row = blockIdx.x;
  const int tid = threadIdx.x;
  const float4 v = reinterpret_cast<const float4*>(x + (size_t)row * D)[tid];
  float s  = v.x + v.y + v.z + v.w;
  float s2 = v.x * v.x + v.y * v.y + v.z * v.z + v.w * v.w;
  #pragma unroll
  for (int off = 32; off > 0; off >>= 1) {
    s  += __shfl_down(s, off);
    s2 += __shfl_down(s2, off);
  }
  __shared__ float red[8];
  const int lane = tid & 63, wv = tid >> 6;
  if (lane == 0) { red[wv] = s; red[4 + wv] = s2; }
  __syncthreads();
  s  = red[0] + red[1] + red[2] + red[3];
  s2 = red[4] + red[5] + red[6] + red[7];
  const float mu   = s * (1.0f / D);
  const float var  = s2 * (1.0f / D) - mu * mu;
  const float rstd = rsqrtf(var + 1e-5f);
  const float4 gv = reinterpret_cast<const float4*>(g)[tid];
  const float4 bv = reinterpret_cast<const float4*>(b)[tid];
  ushort4 o;
  o.x = f2bf((v.x - mu) * rstd * gv.x + bv.x);
  o.y = f2bf((v.y - mu) * rstd * gv.y + bv.y);
  o.z = f2bf((v.z - mu) * rstd * gv.z + bv.z);
  o.w = f2bf((v.w - mu) * rstd * gv.w + bv.w);
  reinterpret_cast<ushort4*>(xn + (size_t)row * D)[tid] = o;
}

// ---------------- bf16 GEMM, C = A @ B^T + bias: 256^2 8-phase v4 ----------
// BM=BN=256, BK=64, 512 threads (8 waves, 2Mx4N), clean 2-tile double buffer.
// Quadrant order (m0n0)(m0n1)(m1n1)(m1n0) -> 12/4/8/4 ds_reads (A reused).
// Staging 1 half-tile/phase into next buffer, issue order == consumption
// order of tile t+1 -> uniform 3-phase slack. Counted vmcnt(4) at end of
// P0/P1/P3 (tail 2/0), never 0 mid-loop. setprio around MFMA. XOR-swizzled
// LDS, XCD-bijective block swizzle. LDS-staged coalesced epilogue; MODE==1
// fuses EMA chunk partials.
static __device__ __forceinline__ s16x8 ldfrag(const u16* b, int row, int ks,
                                               int fkc, int sx) {
  return *reinterpret_cast<const s16x8*>(
      &b[row * 64 + ((((ks << 2) + fkc) ^ sx) << 3)]);
}

template<int MODE>  // 0: fp32 out; 1: bf16 out + EMA chunk partials
__global__ __launch_bounds__(512, 2) void gemm8_k(const u16* __restrict__ A,
                                                  const u16* __restrict__ Bm,
                                                  const float* __restrict__ bias,
                                                  void* __restrict__ Cv,
                                                  const float* __restrict__ alpha,
                                                  float* __restrict__ Lp,
                                                  int M, int N, int K) {
  const int tid  = threadIdx.x;
  const int lane = tid & 63;
  const int wv   = tid >> 6;      // 0..7
  const int wrr  = wv >> 2;       // 0..1  (wave row)
  const int wcc  = wv & 3;        // 0..3  (wave col)
  const int ntN  = N >> 8;
  const int nwg  = (M >> 8) * ntN;
  const int bid  = blockIdx.x;
  const int wgid = (bid & 7) * (nwg >> 3) + (bid >> 3);   // nwg % 8 == 0
  const int mt = wgid / ntN, nt = wgid % ntN;
  const int m0 = mt << 8, n0 = nt << 8;

  __shared__ __align__(16) u16 smem[4 * 16384];   // A0|A1|B0|B1 (u16 units)

  // staging: LDS row l holds global A row amap / B row grow (verified R4/R5).
  const int u   = tid >> 3;
  const int tch = tid & 7;
  const int csw = (tch ^ (u & 7)) << 3;            // inverse-swizzled src col
  const int ldst = u * 64 + (tch << 3);            // linear LDS dest (elem)
  constexpr int amap[4] = {0, 2, 1, 3};
  const u16* gAr[4];
  const u16* gBr[4];
  #pragma unroll
  for (int r = 0; r < 4; ++r) {
    gAr[r] = A + (size_t)(m0 + amap[r] * 64 + u) * K + csw;
    const int l = r * 64 + u;
    const int grow = ((l >> 5) & 3) * 64 + (l >> 7) * 32 + (l & 31);
    gBr[r] = Bm + (size_t)(n0 + grow) * K + csw;
  }

  f32x4 acc[8][4];
  #pragma unroll
  for (int i = 0; i < 8; ++i)
    #pragma unroll
    for (int j = 0; j < 4; ++j) acc[i][j] = f32x4{0.f, 0.f, 0.f, 0.f};

  const int fr  = lane & 15;
  const int fkc = lane >> 4;
  const int sx  = fr & 7;
  const int NK  = K >> 6;   // 16 here

#define ST2(dst, pa, pb, ko) \
  async_copy16(&(dst)[ldst], (pa) + (ko)); \
  async_copy16(&(dst)[ldst + 4096], (pb) + (ko));

  // prologue: tile 0, issue order = consumption order [Ah0, Bh0, Bh1, Ah1]
  {
    u16* A0 = smem;
    u16* B0 = smem + 32768;
    ST2(A0,        gAr[0], gAr[1], 0)
    ST2(B0,        gBr[0], gBr[1], 0)
    ST2(B0 + 8192, gBr[2], gBr[3], 0)
    ST2(A0 + 8192, gAr[2], gAr[3], 0)
  }
  asm volatile("s_waitcnt vmcnt(4)" ::: "memory");
  __builtin_amdgcn_s_barrier();

  s16x8 af[4][2], bfr[2][2];

  for (int kt = 0; kt < NK; ++kt) {
    const int cur = kt & 1;
    const u16* bA = smem + cur * 16384;
    const u16* bB = smem + 32768 + cur * 16384;
    u16* nA = smem + (cur ^ 1) * 16384;
    u16* nB = smem + 32768 + (cur ^ 1) * 16384;
    const bool pf = (kt + 1 < NK);
    const size_t ko1 = (size_t)(kt + 1) << 6;

    // ---- P0: quad (m0,n0). reads Ah0(8)+Bh0(4). stage Ah0(t+1).
    #pragma unroll
    for (int i = 0; i < 4; ++i)
      #pragma unroll
      for (int ks = 0; ks < 2; ++ks)
        af[i][ks] = ldfrag(bA, wrr * 64 + i * 16 + fr, ks, fkc, sx);
    #pragma unroll
    for (int j = 0; j < 2; ++j)
      #pragma unroll
      for (int ks = 0; ks < 2; ++ks)
        bfr[j][ks] = ldfrag(bB, wcc * 32 + j * 16 + fr, ks, fkc, sx);
    if (pf) { ST2(nA, gAr[0], gAr[1], ko1) }
    __builtin_amdgcn_s_barrier();
    __builtin_amdgcn_s_setprio(1);
    #pragma unroll
    for (int i = 0; i < 4; ++i)
      #pragma unroll
      for (int j = 0; j < 2; ++j)
        #pragma unroll
        for (int ks = 0; ks < 2; ++ks)
          acc[i][j] = __builtin_amdgcn_mfma_f32_16x16x32_bf16(
              __builtin_bit_cast(bf16x8, af[i][ks]),
              __builtin_bit_cast(bf16x8, bfr[j][ks]), acc[i][j], 0, 0, 0);
    __builtin_amdgcn_s_setprio(0);
    if (pf) { asm volatile("s_waitcnt vmcnt(4)" ::: "memory"); }
    else    { asm volatile("s_waitcnt vmcnt(2)" ::: "memory"); }
    __builtin_amdgcn_s_barrier();

    // ---- P1: quad (m0,n1). reads Bh1(4), A reused. stage Bh0(t+1).
    #pragma unroll
    for (int j = 0; j < 2; ++j)
      #pragma unroll
      for (int ks = 0; ks < 2; ++ks)
        bfr[j][ks] = ldfrag(bB, 128 + wcc * 32 + j * 16 + fr, ks, fkc, sx);
    if (pf) { ST2(nB, gBr[0], gBr[1], ko1) }
    __builtin_amdgcn_s_barrier();
    __builtin_amdgcn_s_setprio(1);
    #pragma unroll
    for (int i = 0; i < 4; ++i)
      #pragma unroll
      for (int j = 0; j < 2; ++j)
        #pragma unroll
        for (int ks = 0; ks < 2; ++ks)
          acc[i][2 + j] = __builtin_amdgcn_mfma_f32_16x16x32_bf16(
              __builtin_bit_cast(bf16x8, af[i][ks]),
              __builtin_bit_cast(bf16x8, bfr[j][ks]), acc[i][2 + j], 0, 0, 0);
    __builtin_amdgcn_s_setprio(0);
    if (pf) { asm volatile("s_waitcnt vmcnt(4)" ::: "memory"); }
    else    { asm volatile("s_waitcnt vmcnt(0)" ::: "memory"); }
    __builtin_amdgcn_s_barrier();

    // ---- P2: quad (m1,n1). reads Ah1(8), B reused. stage Bh1(t+1).
    #pragma unroll
    for (int i = 0; i < 4; ++i)
      #pragma unroll
      for (int ks = 0; ks < 2; ++ks)
        af[i][ks] = ldfrag(bA, 128 + wrr * 64 + i * 16 + fr, ks, fkc, sx);
    if (pf) { ST2(nB + 8192, gBr[2], gBr[3], ko1) }
    __builtin_amdgcn_s_barrier();
    __builtin_amdgcn_s_setprio(1);
    #pragma unroll
    for (int i = 0; i < 4; ++i)
      #pragma unroll
      for (int j = 0; j < 2; ++j)
        #pragma unroll
        for (int ks = 0; ks < 2; ++ks)
          acc[4 + i][2 + j] = __builtin_amdgcn_mfma_f32_16x16x32_bf16(
              __builtin_bit_cast(bf16x8, af[i][ks]),
              __builtin_bit_cast(bf16x8, bfr[j][ks]), acc[4 + i][2 + j], 0, 0, 0);
    __builtin_amdgcn_s_setprio(0);
    __builtin_amdgcn_s_barrier();

    // ---- P3: quad (m1,n0). reads Bh0(4) again, A reused. stage Ah1(t+1).
    #pragma unroll
    for (int j = 0; j < 2; ++j)
      #pragma unroll
      for (int ks = 0; ks < 2; ++ks)
        bfr[j][ks] = ldfrag(bB, wcc * 32 + j * 16 + fr, ks, fkc, sx);
    if (pf) { ST2(nA + 8192, gAr[2], gAr[3], ko1) }
    __builtin_amdgcn_s_barrier();
    __builtin_amdgcn_s_setprio(1);
    #pragma unroll
    for (int i = 0; i < 4; ++i)
      #pragma unroll
      for (int j = 0; j < 2; ++j)
        #pragma unroll
        for (int ks = 0; ks < 2; ++ks)
          acc[4 + i][j] = __builtin_amdgcn_mfma_f32_16x16x32_bf16(
              __builtin_bit_cast(bf16x8, af[i][ks]),
              __builtin_bit_cast(bf16x8, bfr[j][ks]), acc[4 + i][j], 0, 0, 0);
    __builtin_amdgcn_s_setprio(0);
    if (pf) { asm volatile("s_waitcnt vmcnt(4)" ::: "memory"); }
    __builtin_amdgcn_s_barrier();
  }
#undef ST2

  // ---- epilogue: LDS-staged coalesced C write (+ fused EMA chunk partials) ----
  float* sC = (float*)smem;            // 128 rows x 256 cols fp32 = 128 KiB
  const int cr = (lane >> 4) << 2;
  const int cc = lane & 15;
  float bv[4];
  #pragma unroll
  for (int nj = 0; nj < 4; ++nj) bv[nj] = bias[n0 + wcc * 64 + nj * 16 + cc];

  #pragma unroll
  for (int p = 0; p < 2; ++p) {
    __syncthreads();                   // prev pass / K-loop reads done
    if (wrr == p) {
      #pragma unroll
      for (int mi = 0; mi < 8; ++mi)
        #pragma unroll
        for (int nj = 0; nj < 4; ++nj)
          #pragma unroll
          for (int rr = 0; rr < 4; ++rr) {
            const int row = mi * 16 + cr + rr;
            const int col = wcc * 64 + nj * 16 + cc;
            sC[row * 256 + (col ^ ((row & 4) << 2))] = acc[mi][nj][rr] + bv[nj];
          }
    }
    __syncthreads();
    // coalesced store: 16B/lane
    #pragma unroll 4
    for (int it = 0; it < 16; ++it) {
      const int row  = it * 8 + wv;
      const int col0 = (tid & 63) * 4;
      f32x4 v = *(const f32x4*)&sC[row * 256 + (col0 ^ ((row & 4) << 2))];
      const size_t goff = (size_t)(m0 + p * 128 + row) * N + n0 + col0;
      if (MODE == 1) {
        ushort4 o; o.x = f2bf(v[0]); o.y = f2bf(v[1]); o.z = f2bf(v[2]); o.w = f2bf(v[3]);
        *(ushort4*)&((u16*)Cv)[goff] = o;
      } else {
        *(f32x4*)&((float*)Cv)[goff] = v;
      }
    }
    if (MODE == 1 && tid < 256) {
      // per-chunk EMA local sum over rows 1..127 (row-0 boundary term added
      // exactly by the carry kernel). Chunk == this 128-row pass.
      const int col = tid;
      const int hh = (n0 + col) >> 7;
      const float a = 1.0f / (1.0f + __expf(-alpha[hh]));
      const float rw = 1.0f - a;
      float prev = sC[col];            // row 0 (swizzle bits 0 for row 0)
      float L = 0.f;
      int t = 1;
      for (; t + 8 <= 128; t += 8) {
        float w0 = sC[(t+0)*256 + (col ^ (((t+0)&4)<<2))];
        float w1 = sC[(t+1)*256 + (col ^ (((t+1)&4)<<2))];
        float w2 = sC[(t+2)*256 + (col ^ (((t+2)&4)<<2))];
        float w3 = sC[(t+3)*256 + (col ^ (((t+3)&4)<<2))];
        float w4 = sC[(t+4)*256 + (col ^ (((t+4)&4)<<2))];
        float w5 = sC[(t+5)*256 + (col ^ (((t+5)&4)<<2))];
        float w6 = sC[(t+6)*256 + (col ^ (((t+6)&4)<<2))];
        float w7 = sC[(t+7)*256 + (col ^ (((t+7)&4)<<2))];
        L = rw * L + a * (w0 - prev);
        L = rw * L + a * (w1 - w0);
        L = rw * L + a * (w2 - w1);
        L = rw * L + a * (w3 - w2);
        L = rw * L + a * (w4 - w3);
        L = rw * L + a * (w5 - w4);
        L = rw * L + a * (w6 - w5);
        L = rw * L + a * (w7 - w6);
        prev = w7;
      }
      for (; t < 128; ++t) {
        float w = sC[t*256 + (col ^ ((t&4)<<2))];
        L = rw * L + a * (w - prev); prev = w;
      }
      const int bb = m0 >> 12;
      const int q  = ((m0 >> 7) & 31) + p;
      Lp[((size_t)bb * 32 + q) * 1024 + n0 + col] = L;
    }
  }
}

// ---------------- EMA carry combine (+ exact chunk-boundary terms) ----------------
__global__ __launch_bounds__(256) void ema_carry_k(const u16* __restrict__ xpb,
                                                   const float* __restrict__ alpha,
                                                   const float* __restrict__ init,
                                                   float* __restrict__ carry) {
  const int Dd = 1024, nCh = 32;
  const int idx = blockIdx.x * 256 + threadIdx.x;  // 0..B*D-1
  const int c  = idx & (Dd - 1);
  const int bb = idx >> 10;
  const int h = c >> 7;
  const float a = 1.0f / (1.0f + __expf(-alpha[h]));
  const float r = 1.0f - a;
  float q_ = r, r127 = 1.0f;
  #pragma unroll
  for (int s = 0; s < 7; ++s) { r127 *= q_; q_ *= q_; }
  const float rT = r127 * r;
  float cin = init[c];
  float prevv = cin;                               // v_{-1} for chunk 0
  for (int q = 0; q < nCh; ++q) {
    const size_t rowb = (size_t)bb * 4096 + (size_t)q * 128;
    const float v0 = bf2f(xpb[rowb * Dd + c]);
    const size_t off = ((size_t)bb * nCh + q) * Dd + c;
    const float L = carry[off] + a * r127 * (v0 - prevv);
    carry[off] = cin;                              // incoming O for chunk q
    cin = rT * cin + L;
    prevv = bf2f(xpb[(rowb + 127) * Dd + c]);      // v_{-1} for chunk q+1
  }
}

__global__ __launch_bounds__(256) void ema_apply_k(const u16* __restrict__ xp,
                                                   const float* __restrict__ alpha,
                                                   const float* __restrict__ init,
                                                   const float* __restrict__ carry,
                                                   u16* __restrict__ ob) {
  const int Nn = 4096, Dd = 1024, T = 128, nCh = 32;
  int bid = blockIdx.x;
  const int cg = bid & 1;  bid >>= 1;
  const int q  = bid & 31; bid >>= 5;
  const int bb = bid;
  const int c = cg * 512 + threadIdx.x * 2;
  const int h = c >> 7;
  const float a = 1.0f / (1.0f + __expf(-alpha[h]));
  const float r = 1.0f - a;
  const u16* px = xp + ((size_t)bb * Nn + (size_t)q * T) * Dd + c;
  u16* po = ob + ((size_t)bb * Nn + (size_t)q * T) * Dd + c;
  float2 Oin = *(const float2*)(carry + ((size_t)bb * nCh + q) * Dd + c);
  float O0 = Oin.x, O1 = Oin.y;
  float p0, p1;
  if (q == 0) { p0 = init[c]; p1 = init[c + 1]; }
  else { ushort2 pv = *(const ushort2*)(px - Dd); p0 = bf2f(pv.x); p1 = bf2f(pv.y); }
  #pragma unroll 4
  for (int t = 0; t < T; ++t) {
    ushort2 v = *(const ushort2*)(px + (size_t)t * Dd);
    float v0 = bf2f(v.x), v1 = bf2f(v.y);
    O0 = r * O0 + a * (v0 - p0);
    O1 = r * O1 + a * (v1 - p1);
    p0 = v0; p1 = v1;
    ushort2 o; o.x = f2bf(O0); o.y = f2bf(O1);
    *(ushort2*)(po + (size_t)t * Dd) = o;
  }
}

extern "C" void kernel_launch(void* const* d_in, const int* in_sizes, int n_in,
                              void* d_out, int out_size, void* d_ws, size_t ws_size,
                              hipStream_t stream) {
  const float* x     = (const float*)d_in[0];
  const float* ln_g  = (const float*)d_in[1];
  const float* ln_b  = (const float*)d_in[2];
  const float* w_in  = (const float*)d_in[3];
  const float* b_in  = (const float*)d_in[4];
  const float* init  = (const float*)d_in[5];
  const float* alpha = (const float*)d_in[6];
  const float* w_out = (const float*)d_in[7];
  const float* b_out = (const float*)d_in[8];
  float* out = (float*)d_out;

  const int B = 4, N = 4096, D = 1024;
  const int M = B * N;  // 16384

  char* p = (char*)d_ws;
  u16*   xn  = (u16*)p; p += (size_t)M * D * sizeof(u16);      // 32 MB  LN output bf16
  u16*   wi  = (u16*)p; p += (size_t)D * D * sizeof(u16);      // 2 MB   w_in bf16
  u16*   wo  = (u16*)p; p += (size_t)D * D * sizeof(u16);      // 2 MB   w_out bf16
  u16*   xpb = (u16*)p; p += (size_t)M * D * sizeof(u16);      // 32 MB  project_in out bf16
  float* cr  = (float*)p; p += (size_t)B * 32 * D * sizeof(float); // 512 KB L-partials/carries
  u16*   ob  = (u16*)p;                                         // 32 MB  EMA out bf16

  const int n4 = D * D / 4;
  cvt_k<<<dim3((n4 + 255) / 256), dim3(256), 0, stream>>>(w_in, wi, n4);
  cvt_k<<<dim3((n4 + 255) / 256), dim3(256), 0, stream>>>(w_out, wo, n4);
  ln_k<<<dim3(M), dim3(256), 0, stream>>>(x, ln_g, ln_b, xn);
  gemm8_k<1><<<dim3((M / 256) * (D / 256)), dim3(512), 0, stream>>>(
      xn, wi, b_in, xpb, alpha, cr, M, D, D);
  ema_carry_k<<<dim3(B * D / 256), dim3(256), 0, stream>>>(xpb, alpha, init, cr);
  ema_apply_k<<<dim3(B * 32 * 2), dim3(256), 0, stream>>>(xpb, alpha, init, cr, ob);
  gemm8_k<0><<<dim3((M / 256) * (D / 256)), dim3(512), 0, stream>>>(
      ob, wo, b_out, out, nullptr, nullptr, M, D, D);
}

// Round 8
// 143.769 us; speedup vs baseline: 1.1208x; 1.1178x over previous
//
#include <hip/hip_runtime.h>
#include <stdint.h>

typedef float  f32x4 __attribute__((ext_vector_type(4)));
typedef __bf16 bf16x8 __attribute__((ext_vector_type(8)));
typedef short  s16x8 __attribute__((ext_vector_type(8)));
typedef unsigned short u16;

static __device__ __forceinline__ u16 f2bf(float f) {
  unsigned u = __float_as_uint(f);
  u += 0x7fffu + ((u >> 16) & 1u);
  return (u16)(u >> 16);
}
static __device__ __forceinline__ float bf2f(u16 u) {
  return __uint_as_float(((unsigned)u) << 16);
}

static __device__ __forceinline__ void async_copy16(void* lds, const void* g) {
  __builtin_amdgcn_global_load_lds(
      (const __attribute__((address_space(1))) unsigned int*)g,
      (__attribute__((address_space(3))) unsigned int*)lds, 16, 0, 0);
}

// ---------------- fp32 -> bf16 convert (both weights, one launch) ----------
__global__ __launch_bounds__(256) void cvt2_k(const float* __restrict__ in0,
                                              const float* __restrict__ in1,
                                              u16* __restrict__ out0,
                                              u16* __restrict__ out1, int n4) {
  int i = blockIdx.x * 256 + threadIdx.x;
  const float* in = (i < n4) ? in0 : in1;
  u16* out = (i < n4) ? out0 : out1;
  int idx = (i < n4) ? i : i - n4;
  float4 v = reinterpret_cast<const float4*>(in)[idx];
  ushort4 o;
  o.x = f2bf(v.x); o.y = f2bf(v.y); o.z = f2bf(v.z); o.w = f2bf(v.w);
  reinterpret_cast<ushort4*>(out)[idx] = o;
}

// ---------------- LayerNorm: one block per row, D=1024 ----------------
__global__ __launch_bounds__(256) void ln_k(const float* __restrict__ x,
                                            const float* __restrict__ g,
                                            const float* __restrict__ b,
                                            u16* __restrict__ xn) {
  const int D = 1024;
  const int row = blockIdx.x;
  const int tid = threadIdx.x;
  const float4 v = reinterpret_cast<const float4*>(x + (size_t)row * D)[tid];
  float s  = v.x + v.y + v.z + v.w;
  float s2 = v.x * v.x + v.y * v.y + v.z * v.z + v.w * v.w;
  #pragma unroll
  for (int off = 32; off > 0; off >>= 1) {
    s  += __shfl_down(s, off);
    s2 += __shfl_down(s2, off);
  }
  __shared__ float red[8];
  const int lane = tid & 63, wv = tid >> 6;
  if (lane == 0) { red[wv] = s; red[4 + wv] = s2; }
  __syncthreads();
  s  = red[0] + red[1] + red[2] + red[3];
  s2 = red[4] + red[5] + red[6] + red[7];
  const float mu   = s * (1.0f / D);
  const float var  = s2 * (1.0f / D) - mu * mu;
  const float rstd = rsqrtf(var + 1e-5f);
  const float4 gv = reinterpret_cast<const float4*>(g)[tid];
  const float4 bv = reinterpret_cast<const float4*>(b)[tid];
  ushort4 o;
  o.x = f2bf((v.x - mu) * rstd * gv.x + bv.x);
  o.y = f2bf((v.y - mu) * rstd * gv.y + bv.y);
  o.z = f2bf((v.z - mu) * rstd * gv.z + bv.z);
  o.w = f2bf((v.w - mu) * rstd * gv.w + bv.w);
  reinterpret_cast<ushort4*>(xn + (size_t)row * D)[tid] = o;
}

// ---------------- bf16 GEMM, C = A @ B^T + bias (R2-proven 2-phase) -------
// 128x128 tile, BK=64, double-buffered LDS, XOR-swizzled (linear dest +
// pre-swizzled global src + swizzled read), XCD-bijective block swizzle.
// 4 waves of 64x64, mfma_f32_16x16x32_bf16. LDS-staged coalesced epilogue
// (reuses staging LDS); MODE==1 writes bf16 + fused EMA chunk partials.
template<int MODE>  // 0: fp32 out; 1: bf16 out + EMA partials
__global__ __launch_bounds__(256) void gemm_bt_k(const u16* __restrict__ A,
                                                 const u16* __restrict__ Bm,
                                                 const float* __restrict__ bias,
                                                 void* __restrict__ Cv,
                                                 const float* __restrict__ alpha,
                                                 float* __restrict__ Lp,
                                                 int M, int N, int K) {
  const int tid  = threadIdx.x;
  const int lane = tid & 63;
  const int wv   = tid >> 6;
  const int ntN  = N >> 7;
  const int nwg  = (M >> 7) * ntN;
  const int bid  = blockIdx.x;
  const int wgid = (bid & 7) * (nwg >> 3) + (bid >> 3);   // nwg % 8 == 0
  const int mt = wgid / ntN, nt = wgid % ntN;
  const int m0 = mt << 7, n0 = nt << 7;

  __shared__ __align__(16) u16 smem[32768];   // 64 KiB: sA[2]|sB[2], later sC
  __shared__ float sRed[128];

  // staging: thread t -> row = t>>3 (+32 per round), 16B chunk = t&7.
  // global source inverse-swizzled: LDS slot (row,c) holds chunk c^(row&7).
  const int trow = tid >> 3;
  const int tch  = tid & 7;
  const int csw  = (tch ^ (trow & 7)) << 3;
  const u16* gA = A  + (size_t)(m0 + trow) * K + csw;
  const u16* gB = Bm + (size_t)(n0 + trow) * K + csw;
  const int lofs = trow * 64 + (tch << 3);

  f32x4 acc[4][4];
  #pragma unroll
  for (int i = 0; i < 4; ++i)
    #pragma unroll
    for (int j = 0; j < 4; ++j) acc[i][j] = f32x4{0.f, 0.f, 0.f, 0.f};

  const int wr  = (wv >> 1) << 6;
  const int wc  = (wv & 1) << 6;
  const int fr  = lane & 15;
  const int fkc = lane >> 4;
  const int sx  = fr & 7;

  const int nk = K >> 6;
  int buf = 0;

  // prologue
  #pragma unroll
  for (int r = 0; r < 4; ++r) {
    async_copy16(&smem[lofs + r * 2048], gA + (size_t)r * 32 * K);
    async_copy16(&smem[16384 + lofs + r * 2048], gB + (size_t)r * 32 * K);
  }
  __syncthreads();

  for (int t = 0; t < nk; ++t) {
    if (t + 1 < nk) {
      const size_t ko = (size_t)(t + 1) << 6;
      const int nb = (buf ^ 1) * 8192;
      #pragma unroll
      for (int r = 0; r < 4; ++r) {
        async_copy16(&smem[nb + lofs + r * 2048], gA + ko + (size_t)r * 32 * K);
        async_copy16(&smem[16384 + nb + lofs + r * 2048], gB + ko + (size_t)r * 32 * K);
      }
    }
    const u16* bA = smem + buf * 8192;
    const u16* bB = smem + 16384 + buf * 8192;
    #pragma unroll
    for (int s = 0; s < 2; ++s) {
      const int ch = ((((s << 2) + fkc) ^ sx) << 3);   // swizzled elem offset
      s16x8 af[4], bfr[4];
      #pragma unroll
      for (int i = 0; i < 4; ++i)
        af[i] = *reinterpret_cast<const s16x8*>(&bA[(wr + i * 16 + fr) * 64 + ch]);
      #pragma unroll
      for (int j = 0; j < 4; ++j)
        bfr[j] = *reinterpret_cast<const s16x8*>(&bB[(wc + j * 16 + fr) * 64 + ch]);
      #pragma unroll
      for (int i = 0; i < 4; ++i)
        #pragma unroll
        for (int j = 0; j < 4; ++j)
          acc[i][j] = __builtin_amdgcn_mfma_f32_16x16x32_bf16(
              __builtin_bit_cast(bf16x8, af[i]),
              __builtin_bit_cast(bf16x8, bfr[j]), acc[i][j], 0, 0, 0);
    }
    __syncthreads();   // drains vmcnt(0): next tile staged, buf free to reuse
    buf ^= 1;
  }

  // ---- epilogue: stage C in LDS (reuse staging space), coalesced store ----
  float* sC = (float*)smem;            // 128 x 128 fp32 = 64 KiB
  const int cr = (lane >> 4) << 2;
  const int cc = lane & 15;
  float bv[4];
  #pragma unroll
  for (int nj = 0; nj < 4; ++nj) bv[nj] = bias[n0 + wc + nj * 16 + cc];
  // after final K-iter __syncthreads, all LDS reads are done -> safe to write
  #pragma unroll
  for (int mi = 0; mi < 4; ++mi)
    #pragma unroll
    for (int nj = 0; nj < 4; ++nj)
      #pragma unroll
      for (int rr = 0; rr < 4; ++rr) {
        const int row = wr + mi * 16 + cr + rr;
        const int col = wc + nj * 16 + cc;
        sC[row * 128 + (col ^ ((row & 4) << 2))] = acc[mi][nj][rr] + bv[nj];
      }
  __syncthreads();
  // coalesced store: 16B/lane, full 512B rows
  #pragma unroll 4
  for (int it = 0; it < 16; ++it) {
    const int row  = it * 8 + (tid >> 5);
    const int col0 = (tid & 31) * 4;
    f32x4 v = *(const f32x4*)&sC[row * 128 + (col0 ^ ((row & 4) << 2))];
    const size_t goff = (size_t)(m0 + row) * N + n0 + col0;
    if (MODE == 1) {
      ushort4 o; o.x = f2bf(v[0]); o.y = f2bf(v[1]); o.z = f2bf(v[2]); o.w = f2bf(v[3]);
      *(ushort4*)&((u16*)Cv)[goff] = o;
    } else {
      *(f32x4*)&((float*)Cv)[goff] = v;
    }
  }
  if (MODE == 1) {
    // fused EMA chunk partial over rows 1..127 (chunk == this block's rows).
    // Split: lo half steps 1..63, hi half steps 64..127;
    // combine L = r^64 * L_lo + L_hi. Row-0 boundary term added by carry_k.
    const int col = tid & 127;
    const int hh = (n0 + col) >> 7;
    const float a  = 1.0f / (1.0f + __expf(-alpha[hh]));
    const float rw = 1.0f - a;
    float r64 = rw;
    #pragma unroll
    for (int s = 0; s < 6; ++s) r64 *= r64;      // rw^64
    const bool lo = (tid < 128);
    const int rbase  = lo ? 1 : 64;
    const int nsteps = lo ? 63 : 64;
    float prev = sC[(rbase - 1) * 128 + (col ^ (((rbase - 1) & 4) << 2))];
    float L = 0.f;
    #pragma unroll 8
    for (int t = rbase; t < rbase + 64; ++t) {
      if (t - rbase >= nsteps) break;
      const float w = sC[t * 128 + (col ^ ((t & 4) << 2))];
      L = rw * L + a * (w - prev);
      prev = w;
    }
    if (!lo) sRed[col] = L;
    __syncthreads();
    if (lo) {
      const float Lt = r64 * L + sRed[col];
      const int bb = m0 >> 12;
      const int q  = (m0 >> 7) & 31;
      Lp[((size_t)bb * 32 + q) * 1024 + n0 + col] = Lt;
    }
  }
}

// ---------------- EMA carry combine (+ exact chunk-boundary terms) --------
__global__ __launch_bounds__(256) void ema_carry_k(const u16* __restrict__ xpb,
                                                   const float* __restrict__ alpha,
                                                   const float* __restrict__ init,
                                                   float* __restrict__ carry) {
  const int Dd = 1024, nCh = 32;
  const int idx = blockIdx.x * 256 + threadIdx.x;  // 0..B*D-1
  const int c  = idx & (Dd - 1);
  const int bb = idx >> 10;
  const int h = c >> 7;
  const float a = 1.0f / (1.0f + __expf(-alpha[h]));
  const float r = 1.0f - a;
  float q_ = r, r127 = 1.0f;
  #pragma unroll
  for (int s = 0; s < 7; ++s) { r127 *= q_; q_ *= q_; }
  const float rT = r127 * r;
  float cin = init[c];
  float prevv = cin;                               // v_{-1} for chunk 0
  for (int q = 0; q < nCh; ++q) {
    const size_t rowb = (size_t)bb * 4096 + (size_t)q * 128;
    const float v0 = bf2f(xpb[rowb * Dd + c]);
    const size_t off = ((size_t)bb * nCh + q) * Dd + c;
    const float L = carry[off] + a * r127 * (v0 - prevv);
    carry[off] = cin;                              // incoming O for chunk q
    cin = rT * cin + L;
    prevv = bf2f(xpb[(rowb + 127) * Dd + c]);      // v_{-1} for chunk q+1
  }
}

__global__ __launch_bounds__(256) void ema_apply_k(const u16* __restrict__ xp,
                                                   const float* __restrict__ alpha,
                                                   const float* __restrict__ init,
                                                   const float* __restrict__ carry,
                                                   u16* __restrict__ ob) {
  const int Nn = 4096, Dd = 1024, T = 128, nCh = 32;
  int bid = blockIdx.x;
  const int cg = bid & 1;  bid >>= 1;
  const int q  = bid & 31; bid >>= 5;
  const int bb = bid;
  const int c = cg * 512 + threadIdx.x * 2;
  const int h = c >> 7;
  const float a = 1.0f / (1.0f + __expf(-alpha[h]));
  const float r = 1.0f - a;
  const u16* px = xp + ((size_t)bb * Nn + (size_t)q * T) * Dd + c;
  u16* po = ob + ((size_t)bb * Nn + (size_t)q * T) * Dd + c;
  float2 Oin = *(const float2*)(carry + ((size_t)bb * nCh + q) * Dd + c);
  float O0 = Oin.x, O1 = Oin.y;
  float p0, p1;
  if (q == 0) { p0 = init[c]; p1 = init[c + 1]; }
  else { ushort2 pv = *(const ushort2*)(px - Dd); p0 = bf2f(pv.x); p1 = bf2f(pv.y); }
  #pragma unroll 4
  for (int t = 0; t < T; ++t) {
    ushort2 v = *(const ushort2*)(px + (size_t)t * Dd);
    float v0 = bf2f(v.x), v1 = bf2f(v.y);
    O0 = r * O0 + a * (v0 - p0);
    O1 = r * O1 + a * (v1 - p1);
    p0 = v0; p1 = v1;
    ushort2 o; o.x = f2bf(O0); o.y = f2bf(O1);
    *(ushort2*)(po + (size_t)t * Dd) = o;
  }
}

extern "C" void kernel_launch(void* const* d_in, const int* in_sizes, int n_in,
                              void* d_out, int out_size, void* d_ws, size_t ws_size,
                              hipStream_t stream) {
  const float* x     = (const float*)d_in[0];
  const float* ln_g  = (const float*)d_in[1];
  const float* ln_b  = (const float*)d_in[2];
  const float* w_in  = (const float*)d_in[3];
  const float* b_in  = (const float*)d_in[4];
  const float* init  = (const float*)d_in[5];
  const float* alpha = (const float*)d_in[6];
  const float* w_out = (const float*)d_in[7];
  const float* b_out = (const float*)d_in[8];
  float* out = (float*)d_out;

  const int B = 4, N = 4096, D = 1024;
  const int M = B * N;  // 16384

  char* p = (char*)d_ws;
  u16*   xn  = (u16*)p; p += (size_t)M * D * sizeof(u16);      // 32 MB  LN out bf16
  u16*   wi  = (u16*)p; p += (size_t)D * D * sizeof(u16);      // 2 MB   w_in bf16
  u16*   wo  = (u16*)p; p += (size_t)D * D * sizeof(u16);      // 2 MB   w_out bf16
  u16*   xpb = (u16*)p; p += (size_t)M * D * sizeof(u16);      // 32 MB  xp bf16
  float* cr  = (float*)p; p += (size_t)B * 32 * D * sizeof(float); // 512 KB partials/carries
  u16*   ob  = (u16*)p;                                         // 32 MB  EMA out bf16

  const int n4 = D * D / 4;
  cvt2_k<<<dim3(2 * n4 / 256), dim3(256), 0, stream>>>(w_in, w_out, wi, wo, n4);
  ln_k<<<dim3(M), dim3(256), 0, stream>>>(x, ln_g, ln_b, xn);
  gemm_bt_k<1><<<dim3((M / 128) * (D / 128)), dim3(256), 0, stream>>>(
      xn, wi, b_in, xpb, alpha, cr, M, D, D);
  ema_carry_k<<<dim3(B * D / 256), dim3(256), 0, stream>>>(xpb, alpha, init, cr);
  ema_apply_k<<<dim3(B * 32 * 2), dim3(256), 0, stream>>>(xpb, alpha, init, cr, ob);
  gemm_bt_k<0><<<dim3((M / 128) * (D / 128)), dim3(256), 0, stream>>>(
      ob, wo, b_out, out, nullptr, nullptr, M, D, D);
}

// Round 9
// 138.765 us; speedup vs baseline: 1.1612x; 1.0361x over previous
//
#include <hip/hip_runtime.h>
#include <stdint.h>

typedef float  f32x4 __attribute__((ext_vector_type(4)));
typedef __bf16 bf16x8 __attribute__((ext_vector_type(8)));
typedef short  s16x8 __attribute__((ext_vector_type(8)));
typedef unsigned short u16;

static __device__ __forceinline__ u16 f2bf(float f) {
  unsigned u = __float_as_uint(f);
  u += 0x7fffu + ((u >> 16) & 1u);
  return (u16)(u >> 16);
}
static __device__ __forceinline__ float bf2f(u16 u) {
  return __uint_as_float(((unsigned)u) << 16);
}

static __device__ __forceinline__ void async_copy16(void* lds, const void* g) {
  __builtin_amdgcn_global_load_lds(
      (const __attribute__((address_space(1))) unsigned int*)g,
      (__attribute__((address_space(3))) unsigned int*)lds, 16, 0, 0);
}

// ---------------- fp32 -> bf16 convert (both weights, one launch) ----------
__global__ __launch_bounds__(256) void cvt2_k(const float* __restrict__ in0,
                                              const float* __restrict__ in1,
                                              u16* __restrict__ out0,
                                              u16* __restrict__ out1, int n4) {
  int i = blockIdx.x * 256 + threadIdx.x;
  const float* in = (i < n4) ? in0 : in1;
  u16* out = (i < n4) ? out0 : out1;
  int idx = (i < n4) ? i : i - n4;
  float4 v = reinterpret_cast<const float4*>(in)[idx];
  ushort4 o;
  o.x = f2bf(v.x); o.y = f2bf(v.y); o.z = f2bf(v.z); o.w = f2bf(v.w);
  reinterpret_cast<ushort4*>(out)[idx] = o;
}

// ---------------- LayerNorm: one block per row, D=1024 ----------------
__global__ __launch_bounds__(256) void ln_k(const float* __restrict__ x,
                                            const float* __restrict__ g,
                                            const float* __restrict__ b,
                                            u16* __restrict__ xn) {
  const int D = 1024;
  const int row = blockIdx.x;
  const int tid = threadIdx.x;
  const float4 v = reinterpret_cast<const float4*>(x + (size_t)row * D)[tid];
  float s  = v.x + v.y + v.z + v.w;
  float s2 = v.x * v.x + v.y * v.y + v.z * v.z + v.w * v.w;
  #pragma unroll
  for (int off = 32; off > 0; off >>= 1) {
    s  += __shfl_down(s, off);
    s2 += __shfl_down(s2, off);
  }
  __shared__ float red[8];
  const int lane = tid & 63, wv = tid >> 6;
  if (lane == 0) { red[wv] = s; red[4 + wv] = s2; }
  __syncthreads();
  s  = red[0] + red[1] + red[2] + red[3];
  s2 = red[4] + red[5] + red[6] + red[7];
  const float mu   = s * (1.0f / D);
  const float var  = s2 * (1.0f / D) - mu * mu;
  const float rstd = rsqrtf(var + 1e-5f);
  const float4 gv = reinterpret_cast<const float4*>(g)[tid];
  const float4 bv = reinterpret_cast<const float4*>(b)[tid];
  ushort4 o;
  o.x = f2bf((v.x - mu) * rstd * gv.x + bv.x);
  o.y = f2bf((v.y - mu) * rstd * gv.y + bv.y);
  o.z = f2bf((v.z - mu) * rstd * gv.z + bv.z);
  o.w = f2bf((v.w - mu) * rstd * gv.w + bv.w);
  reinterpret_cast<ushort4*>(xn + (size_t)row * D)[tid] = o;
}

// ---------------- bf16 GEMM, C = A @ B^T + bias: 256^2 2-PHASE -------------
// BM=BN=256, BK=64, 512 threads (8 waves 2Mx4N), double-buffered 128 KiB LDS,
// ONE __syncthreads per K-step (R2/R8-proven schedule, scaled). XOR-swizzled
// LDS (linear dest + pre-swizzled src + swizzled read), XCD-bijective block
// swizzle. LDS-staged coalesced epilogue in 2 passes of 128 rows; MODE==1
// writes bf16 + fused EMA chunk partials (one chunk per pass).
template<int MODE>  // 0: fp32 out; 1: bf16 out + EMA partials
__global__ __launch_bounds__(512, 2) void gemm_bt_k(const u16* __restrict__ A,
                                                    const u16* __restrict__ Bm,
                                                    const float* __restrict__ bias,
                                                    void* __restrict__ Cv,
                                                    const float* __restrict__ alpha,
                                                    float* __restrict__ Lp,
                                                    int M, int N, int K) {
  const int tid  = threadIdx.x;
  const int lane = tid & 63;
  const int wv   = tid >> 6;      // 0..7
  const int wrr  = wv >> 2;       // 0..1  wave m-half
  const int wcc  = wv & 3;        // 0..3  wave n-quarter
  const int ntN  = N >> 8;
  const int nwg  = (M >> 8) * ntN;
  const int bid  = blockIdx.x;
  const int wgid = (bid & 7) * (nwg >> 3) + (bid >> 3);   // nwg % 8 == 0
  const int mt = wgid / ntN, nt = wgid % ntN;
  const int m0 = mt << 8, n0 = nt << 8;

  __shared__ __align__(16) u16 smem[65536];   // 128 KiB: A dbuf | B dbuf; later sC
  __shared__ float sRed[256];

  // staging: round r covers rows [64r,64r+64); thread: u=tid>>3, chunk tch=tid&7.
  // global src inverse-swizzled; LDS dest linear (wave-uniform base + lane*16).
  const int u   = tid >> 3;
  const int tch = tid & 7;
  const int csw = (tch ^ (u & 7)) << 3;
  const int lofs = u * 64 + (tch << 3);
  const u16* gA = A  + (size_t)(m0 + u) * K + csw;
  const u16* gB = Bm + (size_t)(n0 + u) * K + csw;

  f32x4 acc[8][4];
  #pragma unroll
  for (int i = 0; i < 8; ++i)
    #pragma unroll
    for (int j = 0; j < 4; ++j) acc[i][j] = f32x4{0.f, 0.f, 0.f, 0.f};

  const int fr  = lane & 15;
  const int fkc = lane >> 4;
  const int sx  = fr & 7;
  const int nk  = K >> 6;
  int buf = 0;
  // LDS element offsets: A buffers at 0 / 16384, B at 32768 / 49152

  // prologue: stage tile 0 into buf 0
  #pragma unroll
  for (int r = 0; r < 4; ++r) {
    async_copy16(&smem[lofs + r * 4096], gA + (size_t)(r * 64) * K);
    async_copy16(&smem[32768 + lofs + r * 4096], gB + (size_t)(r * 64) * K);
  }
  __syncthreads();

  for (int t = 0; t < nk; ++t) {
    if (t + 1 < nk) {
      const size_t ko = (size_t)(t + 1) << 6;
      const int nb = (buf ^ 1) * 16384;
      #pragma unroll
      for (int r = 0; r < 4; ++r) {
        async_copy16(&smem[nb + lofs + r * 4096], gA + ko + (size_t)(r * 64) * K);
        async_copy16(&smem[32768 + nb + lofs + r * 4096], gB + ko + (size_t)(r * 64) * K);
      }
    }
    const u16* bA = smem + buf * 16384;
    const u16* bB = smem + 32768 + buf * 16384;
    #pragma unroll
    for (int s = 0; s < 2; ++s) {
      const int ch = ((((s << 2) + fkc) ^ sx) << 3);   // swizzled elem offset
      s16x8 af[8], bfr[4];
      #pragma unroll
      for (int i = 0; i < 8; ++i)
        af[i] = *reinterpret_cast<const s16x8*>(
            &bA[(wrr * 128 + i * 16 + fr) * 64 + ch]);
      #pragma unroll
      for (int j = 0; j < 4; ++j)
        bfr[j] = *reinterpret_cast<const s16x8*>(
            &bB[(wcc * 64 + j * 16 + fr) * 64 + ch]);
      #pragma unroll
      for (int i = 0; i < 8; ++i)
        #pragma unroll
        for (int j = 0; j < 4; ++j)
          acc[i][j] = __builtin_amdgcn_mfma_f32_16x16x32_bf16(
              __builtin_bit_cast(bf16x8, af[i]),
              __builtin_bit_cast(bf16x8, bfr[j]), acc[i][j], 0, 0, 0);
    }
    __syncthreads();   // drains vmcnt(0): next tile staged, buf reusable
    buf ^= 1;
  }

  // ---- epilogue: 2 passes of 128 rows through LDS, coalesced stores -------
  float* sC = (float*)smem;            // 128 x 256 fp32 = 128 KiB
  const int cr = (lane >> 4) << 2;
  const int cc = lane & 15;
  float bv[4];
  #pragma unroll
  for (int nj = 0; nj < 4; ++nj) bv[nj] = bias[n0 + wcc * 64 + nj * 16 + cc];

  #pragma unroll
  for (int p = 0; p < 2; ++p) {
    __syncthreads();                   // K-loop / previous pass reads done
    if (wrr == p) {
      #pragma unroll
      for (int mi = 0; mi < 8; ++mi)
        #pragma unroll
        for (int nj = 0; nj < 4; ++nj)
          #pragma unroll
          for (int rr = 0; rr < 4; ++rr) {
            const int row = mi * 16 + cr + rr;
            const int col = wcc * 64 + nj * 16 + cc;
            sC[row * 256 + (col ^ ((row & 4) << 2))] = acc[mi][nj][rr] + bv[nj];
          }
    }
    __syncthreads();
    // coalesced store: 16B/lane, 1KB rows
    #pragma unroll 4
    for (int it = 0; it < 16; ++it) {
      const int row  = it * 8 + (tid >> 6);
      const int col0 = (tid & 63) * 4;
      f32x4 v = *(const f32x4*)&sC[row * 256 + (col0 ^ ((row & 4) << 2))];
      const size_t goff = (size_t)(m0 + p * 128 + row) * N + n0 + col0;
      if (MODE == 1) {
        ushort4 o; o.x = f2bf(v[0]); o.y = f2bf(v[1]); o.z = f2bf(v[2]); o.w = f2bf(v[3]);
        *(ushort4*)&((u16*)Cv)[goff] = o;
      } else {
        *(f32x4*)&((float*)Cv)[goff] = v;
      }
    }
    if (MODE == 1) {
      // fused EMA chunk partial over rows 1..127 (chunk == this 128-row pass).
      // lo half (tid<256): steps 1..63 for col=tid; hi half: steps 64..127 for
      // col=tid-256. Combine L = r^64*L_lo + L_hi. Row-0 boundary via carry_k.
      const int col = tid & 255;
      const int hh = (n0 + col) >> 7;
      const float a  = 1.0f / (1.0f + __expf(-alpha[hh]));
      const float rw = 1.0f - a;
      float r64 = rw;
      #pragma unroll
      for (int s = 0; s < 6; ++s) r64 *= r64;      // rw^64
      const bool lo = (tid < 256);
      const int rbase  = lo ? 1 : 64;
      const int nsteps = lo ? 63 : 64;
      float prev = sC[(rbase - 1) * 256 + (col ^ (((rbase - 1) & 4) << 2))];
      float L = 0.f;
      #pragma unroll 8
      for (int t = rbase; t < rbase + 64; ++t) {
        if (t - rbase >= nsteps) break;
        const float w = sC[t * 256 + (col ^ ((t & 4) << 2))];
        L = rw * L + a * (w - prev);
        prev = w;
      }
      if (!lo) sRed[col] = L;
      __syncthreads();
      if (lo) {
        const float Lt = r64 * L + sRed[col];
        const int bb = m0 >> 12;
        const int q  = ((m0 >> 7) & 31) + p;
        Lp[((size_t)bb * 32 + q) * 1024 + n0 + col] = Lt;
      }
    }
  }
}

// ---------------- EMA carry combine (+ exact chunk-boundary terms) --------
__global__ __launch_bounds__(256) void ema_carry_k(const u16* __restrict__ xpb,
                                                   const float* __restrict__ alpha,
                                                   const float* __restrict__ init,
                                                   float* __restrict__ carry) {
  const int Dd = 1024, nCh = 32;
  const int idx = blockIdx.x * 256 + threadIdx.x;  // 0..B*D-1
  const int c  = idx & (Dd - 1);
  const int bb = idx >> 10;
  const int h = c >> 7;
  const float a = 1.0f / (1.0f + __expf(-alpha[h]));
  const float r = 1.0f - a;
  float q_ = r, r127 = 1.0f;
  #pragma unroll
  for (int s = 0; s < 7; ++s) { r127 *= q_; q_ *= q_; }
  const float rT = r127 * r;
  float cin = init[c];
  float prevv = cin;                               // v_{-1} for chunk 0
  for (int q = 0; q < nCh; ++q) {
    const size_t rowb = (size_t)bb * 4096 + (size_t)q * 128;
    const float v0 = bf2f(xpb[rowb * Dd + c]);
    const size_t off = ((size_t)bb * nCh + q) * Dd + c;
    const float L = carry[off] + a * r127 * (v0 - prevv);
    carry[off] = cin;                              // incoming O for chunk q
    cin = rT * cin + L;
    prevv = bf2f(xpb[(rowb + 127) * Dd + c]);      // v_{-1} for chunk q+1
  }
}

__global__ __launch_bounds__(256) void ema_apply_k(const u16* __restrict__ xp,
                                                   const float* __restrict__ alpha,
                                                   const float* __restrict__ init,
                                                   const float* __restrict__ carry,
                                                   u16* __restrict__ ob) {
  const int Nn = 4096, Dd = 1024, T = 128, nCh = 32;
  int bid = blockIdx.x;
  const int cg = bid & 1;  bid >>= 1;
  const int q  = bid & 31; bid >>= 5;
  const int bb = bid;
  const int c = cg * 512 + threadIdx.x * 2;
  const int h = c >> 7;
  const float a = 1.0f / (1.0f + __expf(-alpha[h]));
  const float r = 1.0f - a;
  const u16* px = xp + ((size_t)bb * Nn + (size_t)q * T) * Dd + c;
  u16* po = ob + ((size_t)bb * Nn + (size_t)q * T) * Dd + c;
  float2 Oin = *(const float2*)(carry + ((size_t)bb * nCh + q) * Dd + c);
  float O0 = Oin.x, O1 = Oin.y;
  float p0, p1;
  if (q == 0) { p0 = init[c]; p1 = init[c + 1]; }
  else { ushort2 pv = *(const ushort2*)(px - Dd); p0 = bf2f(pv.x); p1 = bf2f(pv.y); }
  #pragma unroll 4
  for (int t = 0; t < T; ++t) {
    ushort2 v = *(const ushort2*)(px + (size_t)t * Dd);
    float v0 = bf2f(v.x), v1 = bf2f(v.y);
    O0 = r * O0 + a * (v0 - p0);
    O1 = r * O1 + a * (v1 - p1);
    p0 = v0; p1 = v1;
    ushort2 o; o.x = f2bf(O0); o.y = f2bf(O1);
    *(ushort2*)(po + (size_t)t * Dd) = o;
  }
}

extern "C" void kernel_launch(void* const* d_in, const int* in_sizes, int n_in,
                              void* d_out, int out_size, void* d_ws, size_t ws_size,
                              hipStream_t stream) {
  const float* x     = (const float*)d_in[0];
  const float* ln_g  = (const float*)d_in[1];
  const float* ln_b  = (const float*)d_in[2];
  const float* w_in  = (const float*)d_in[3];
  const float* b_in  = (const float*)d_in[4];
  const float* init  = (const float*)d_in[5];
  const float* alpha = (const float*)d_in[6];
  const float* w_out = (const float*)d_in[7];
  const float* b_out = (const float*)d_in[8];
  float* out = (float*)d_out;

  const int B = 4, N = 4096, D = 1024;
  const int M = B * N;  // 16384

  char* p = (char*)d_ws;
  u16*   xn  = (u16*)p; p += (size_t)M * D * sizeof(u16);      // 32 MB  LN out bf16
  u16*   wi  = (u16*)p; p += (size_t)D * D * sizeof(u16);      // 2 MB   w_in bf16
  u16*   wo  = (u16*)p; p += (size_t)D * D * sizeof(u16);      // 2 MB   w_out bf16
  u16*   xpb = (u16*)p; p += (size_t)M * D * sizeof(u16);      // 32 MB  xp bf16
  float* cr  = (float*)p; p += (size_t)B * 32 * D * sizeof(float); // 512 KB partials/carries
  u16*   ob  = (u16*)p;                                         // 32 MB  EMA out bf16

  const int n4 = D * D / 4;
  cvt2_k<<<dim3(2 * n4 / 256), dim3(256), 0, stream>>>(w_in, w_out, wi, wo, n4);
  ln_k<<<dim3(M), dim3(256), 0, stream>>>(x, ln_g, ln_b, xn);
  gemm_bt_k<1><<<dim3((M / 256) * (D / 256)), dim3(512), 0, stream>>>(
      xn, wi, b_in, xpb, alpha, cr, M, D, D);
  ema_carry_k<<<dim3(B * D / 256), dim3(256), 0, stream>>>(xpb, alpha, init, cr);
  ema_apply_k<<<dim3(B * 32 * 2), dim3(256), 0, stream>>>(xpb, alpha, init, cr, ob);
  gemm_bt_k<0><<<dim3((M / 256) * (D / 256)), dim3(512), 0, stream>>>(
      ob, wo, b_out, out, nullptr, nullptr, M, D, D);
}